// Round 3
// baseline (259.155 us; speedup 1.0000x reference)
//
#include <hip/hip_runtime.h>
#include <hip/hip_bf16.h>
#include <cstdint>

#define NPTS 4096
#define NB 8
#define KNN 20

__device__ __forceinline__ float lrelu(float x) { return x >= 0.0f ? x : 0.2f * x; }

// monotone float<->uint mapping for atomicMax on floats
__device__ __forceinline__ uint32_t enc_f32(float f) {
    uint32_t u = __float_as_uint(f);
    return (u & 0x80000000u) ? ~u : (u | 0x80000000u);
}
__device__ __forceinline__ float dec_f32(uint32_t u) {
    return (u & 0x80000000u) ? __uint_as_float(u ^ 0x80000000u) : __uint_as_float(~u);
}

// ---------------------------------------------------------------------------
// K1: fused kNN (top-20 smallest sq-dist, ties -> smaller index) + EdgeConv
//     (6->64) + max over k.  1024-thread blocks (16 waves) sharing one 64 KB
//     pts tile -> 2 blocks/CU = 8 waves/SIMD.  Per-lane top-3, max/min value
//     updates.  4 rows per wave interleaved.
// ---------------------------------------------------------------------------
__global__ __launch_bounds__(1024, 8) void k1_knn_edge(
        const float* __restrict__ x,
        const float* __restrict__ W0, const float* __restrict__ b0,
        const float* __restrict__ s0, const float* __restrict__ t0,
        float* __restrict__ H0)
{
    __shared__ float4 pts[NPTS];          // x,y,z,xx   (64 KB)
    __shared__ float sW0[64 * 6];
    __shared__ float sB[64], sS[64], sT[64];

    const int blk = blockIdx.x;
    const int b = blk >> 6;               // 64 blocks per batch
    const int rowbase = (blk & 63) << 6;  // 64 rows per block
    const int t = threadIdx.x;
    const int lane = t & 63;
    const int w = t >> 6;                 // wave 0..15

    const float* xb = x + (size_t)b * (NPTS * 3);
    for (int i = t; i < NPTS; i += 1024) {
        float x0 = xb[3 * i], x1 = xb[3 * i + 1], x2 = xb[3 * i + 2];
        // xx exactly as reference: (x0*x0 + x1*x1) + x2*x2, no fma
        float xx = __fadd_rn(__fadd_rn(__fmul_rn(x0, x0), __fmul_rn(x1, x1)),
                             __fmul_rn(x2, x2));
        pts[i] = make_float4(x0, x1, x2, xx);
    }
    if (t < 64) {
        #pragma unroll
        for (int c = 0; c < 6; c++) sW0[t * 6 + c] = W0[t * 6 + c];
        sB[t] = b0[t]; sS[t] = s0[t]; sT[t] = t0[t];
    }
    __syncthreads();

    const int r0 = rowbase + w * 4;

    // per-lane sorted top-3 (descending s; ties keep earlier index)
    float l0s[4], l1s[4], l2s[4];
    int   l0i[4], l1i[4], l2i[4];
    #pragma unroll
    for (int rr = 0; rr < 4; rr++) {
        l0s[rr] = l1s[rr] = l2s[rr] = -INFINITY;
        l0i[rr] = l1i[rr] = l2i[rr] = 0x7FFFFFFF;
    }

    // ---- scan (q held in registers only here) ----
    {
        float4 q[4];
        #pragma unroll
        for (int rr = 0; rr < 4; rr++) q[rr] = pts[r0 + rr];

        #pragma unroll 2
        for (int j = 0; j < 64; j++) {
            const int m = (j << 6) | lane;
            const float4 p = pts[m];
            #pragma unroll
            for (int rr = 0; rr < 4; rr++) {
                float dot = __fadd_rn(__fadd_rn(__fmul_rn(q[rr].x, p.x),
                                                __fmul_rn(q[rr].y, p.y)),
                                      __fmul_rn(q[rr].z, p.z));
                float inner = __fmul_rn(-2.0f, dot);
                float s = __fsub_rn(__fsub_rn(-q[rr].w, inner), p.w);
                bool g0 = s > l0s[rr], g1 = s > l1s[rr], g2 = s > l2s[rr];
                l2s[rr] = fmaxf(fminf(s, l1s[rr]), l2s[rr]);
                l2i[rr] = g1 ? l1i[rr] : (g2 ? m : l2i[rr]);
                l1s[rr] = fmaxf(fminf(s, l0s[rr]), l1s[rr]);
                l1i[rr] = g0 ? l0i[rr] : (g1 ? m : l1i[rr]);
                l0s[rr] = fmaxf(s, l0s[rr]);
                l0i[rr] = g0 ? m : l0i[rr];
            }
        }
    }

    // weights for the consume phase (kept out of scan scope to cut pressure)
    const float wa0 = sW0[lane * 6 + 0], wa1 = sW0[lane * 6 + 1], wa2 = sW0[lane * 6 + 2];

    // ---- merge: 20 rounds of wave argmax, 4 rows interleaved ----
    float mmax[4];
    int cnt[4];
    #pragma unroll
    for (int rr = 0; rr < 4; rr++) { mmax[rr] = -INFINITY; cnt[rr] = 0; }

    for (int rd = 0; rd < KNN; rd++) {
        float bs[4];
        #pragma unroll
        for (int rr = 0; rr < 4; rr++) bs[rr] = l0s[rr];
        #pragma unroll
        for (int st = 0; st < 6; st++) {
            const int off = 32 >> st;
            #pragma unroll
            for (int rr = 0; rr < 4; rr++)
                bs[rr] = fmaxf(bs[rr], __shfl_xor(bs[rr], off));
        }
        int bi[4];
        #pragma unroll
        for (int rr = 0; rr < 4; rr++) {
            unsigned long long mask = __ballot(l0s[rr] == bs[rr]);
            if (__popcll(mask) == 1) {
                int owner = __ffsll(mask) - 1;
                bi[rr] = __builtin_amdgcn_readlane(l0i[rr], owner);
            } else {
                int cand = (l0s[rr] == bs[rr]) ? l0i[rr] : 0x7FFFFFFF;
                #pragma unroll
                for (int off = 32; off >= 1; off >>= 1)
                    cand = min(cand, __shfl_xor(cand, off));
                bi[rr] = cand;
            }
        }
        #pragma unroll
        for (int rr = 0; rr < 4; rr++) {
            const float4 p = pts[bi[rr]];
            float dotp = wa0 * p.x + wa1 * p.y + wa2 * p.z;
            mmax[rr] = fmaxf(mmax[rr], dotp);
            bool own = (l0s[rr] == bs[rr]) && (l0i[rr] == bi[rr]);
            cnt[rr] += own ? 1 : 0;
            l0s[rr] = own ? l1s[rr] : l0s[rr]; l0i[rr] = own ? l1i[rr] : l0i[rr];
            l1s[rr] = own ? l2s[rr] : l1s[rr]; l1i[rr] = own ? l2i[rr] : l1i[rr];
            l2s[rr] = own ? -INFINITY : l2s[rr];
            bool flag = own && (cnt[rr] == 3);   // lane exhausted its top-3
            if (__any(flag)) {
                // cold path (~0.2/row): refill head with true next-best
                const float4 qq = pts[r0 + rr];
                const float ps = bs[rr]; const int pm = bi[rr];
                float ns = -INFINITY; int ni = 0x7FFFFFFF;
                for (int j = 0; j < 64; j++) {
                    const int m = (j << 6) | lane;
                    const float4 p2 = pts[m];
                    float dot2 = __fadd_rn(__fadd_rn(__fmul_rn(qq.x, p2.x),
                                                     __fmul_rn(qq.y, p2.y)),
                                           __fmul_rn(qq.z, p2.z));
                    float s2 = __fsub_rn(__fsub_rn(-qq.w, __fmul_rn(-2.0f, dot2)), p2.w);
                    bool worse = (s2 < ps) || (s2 == ps && m > pm);
                    bool bett  = (s2 > ns) || (s2 == ns && m < ni);
                    if (worse && bett) { ns = s2; ni = m; }
                }
                if (flag) { l0s[rr] = ns; l0i[rr] = ni; cnt[rr] = 2; }
            }
        }
    }

    // conv = max_k(W0a.p_k) + (W0b-W0a).q ; (conv+b)*s+t ; lrelu.
    // s0>0 and lrelu monotone => max commutes past affine+activation.
    const float wd0 = sW0[lane * 6 + 3] - wa0;
    const float wd1 = sW0[lane * 6 + 4] - wa1;
    const float wd2 = sW0[lane * 6 + 5] - wa2;
    #pragma unroll
    for (int rr = 0; rr < 4; rr++) {
        const float4 q = pts[r0 + rr];
        float cterm = wd0 * q.x + wd1 * q.y + wd2 * q.z;
        float z = (mmax[rr] + cterm + sB[lane]) * sS[lane] + sT[lane];
        H0[((size_t)(b * NPTS) + r0 + rr) * 64 + lane] = lrelu(z);
    }
}

// ---------------------------------------------------------------------------
// K2: pconv chain 64->64->128->128 + max over points.  1024 blocks x 256 thr
//     (4 blocks/CU, 16 waves/CU).  Weights straight from global (L2-cached,
//     broadcast across point-slot lanes); only h tiles in LDS (~26 KB).
//     Thread = (ps 0..15, og 0..15); each thread handles pts {ps, ps+16}.
// ---------------------------------------------------------------------------
__global__ __launch_bounds__(256) void k2_mlp(
        const float* __restrict__ H0,
        const float* __restrict__ W1, const float* __restrict__ b1,
        const float* __restrict__ s1, const float* __restrict__ t1,
        const float* __restrict__ W2, const float* __restrict__ b2,
        const float* __restrict__ s2, const float* __restrict__ t2,
        const float* __restrict__ W3, const float* __restrict__ b3,
        const float* __restrict__ s3, const float* __restrict__ t3,
        uint32_t* __restrict__ gmax)
{
    __shared__ float A[32 * 132];     // h0 (64c) then aliased h2 (128c), stride 132
    __shared__ float h1[32 * 68];     // stride 68
    __shared__ uint32_t bmax[128];

    const int t = threadIdx.x;
    const int blk = blockIdx.x;
    const int b = blk >> 7;               // 128 blocks per batch
    const int pbase = (blk & 127) * 32;   // 32 points per block

    const int ps = t & 15;
    const int og = t >> 4;

    // stage h0 tile [32 pts][64 ch] -> A[p][c] (stride 132)
    {
        const float4* src = (const float4*)&H0[((size_t)(b * NPTS) + pbase) * 64];
        #pragma unroll
        for (int k = 0; k < 2; k++) {
            int i4 = t * 2 + k;           // 512 float4s total
            int p = i4 >> 4, c = (i4 & 15) * 4;
            *(float4*)&A[p * 132 + c] = src[i4];
        }
    }
    if (t < 128) bmax[t] = 0u;
    __syncthreads();

    // ---- L1: 64 -> 64 ; thread outs o = og*4 + [0..4) for pts ps, ps+16 ----
    {
        float accA[4] = {0.f, 0.f, 0.f, 0.f};
        float accB[4] = {0.f, 0.f, 0.f, 0.f};
        for (int c = 0; c < 64; c += 4) {
            float4 hA = *(const float4*)&A[ps * 132 + c];
            float4 hB = *(const float4*)&A[(ps + 16) * 132 + c];
            #pragma unroll
            for (int r = 0; r < 4; r++) {
                float4 wv = *(const float4*)&W1[(og * 4 + r) * 64 + c];
                accA[r] += hA.x * wv.x + hA.y * wv.y + hA.z * wv.z + hA.w * wv.w;
                accB[r] += hB.x * wv.x + hB.y * wv.y + hB.z * wv.z + hB.w * wv.w;
            }
        }
        float4 oA, oB;
        float* pA = (float*)&oA; float* pB = (float*)&oB;
        #pragma unroll
        for (int r = 0; r < 4; r++) {
            int o = og * 4 + r;
            float bb = b1[o], ss = s1[o], tt = t1[o];
            pA[r] = lrelu((accA[r] + bb) * ss + tt);
            pB[r] = lrelu((accB[r] + bb) * ss + tt);
        }
        *(float4*)&h1[ps * 68 + og * 4] = oA;
        *(float4*)&h1[(ps + 16) * 68 + og * 4] = oB;
    }
    __syncthreads();

    // ---- L2: 64 -> 128 ; thread outs o = og*8 + [0..8) ; writes h2 into A ----
    {
        float accA[8], accB[8];
        #pragma unroll
        for (int r = 0; r < 8; r++) { accA[r] = 0.f; accB[r] = 0.f; }
        for (int c = 0; c < 64; c += 4) {
            float4 hA = *(const float4*)&h1[ps * 68 + c];
            float4 hB = *(const float4*)&h1[(ps + 16) * 68 + c];
            #pragma unroll
            for (int r = 0; r < 8; r++) {
                float4 wv = *(const float4*)&W2[(og * 8 + r) * 64 + c];
                accA[r] += hA.x * wv.x + hA.y * wv.y + hA.z * wv.z + hA.w * wv.w;
                accB[r] += hB.x * wv.x + hB.y * wv.y + hB.z * wv.z + hB.w * wv.w;
            }
        }
        float4 oA[2], oB[2];
        float* pA = (float*)oA; float* pB = (float*)oB;
        #pragma unroll
        for (int r = 0; r < 8; r++) {
            int o = og * 8 + r;
            float bb = b2[o], ss = s2[o], tt = t2[o];
            pA[r] = lrelu((accA[r] + bb) * ss + tt);
            pB[r] = lrelu((accB[r] + bb) * ss + tt);
        }
        __syncthreads();   // everyone done reading A (h0) before overwriting
        *(float4*)&A[ps * 132 + og * 8]            = oA[0];
        *(float4*)&A[ps * 132 + og * 8 + 4]        = oA[1];
        *(float4*)&A[(ps + 16) * 132 + og * 8]     = oB[0];
        *(float4*)&A[(ps + 16) * 132 + og * 8 + 4] = oB[1];
    }
    __syncthreads();

    // ---- L3: 128 -> 128 ; thread outs o = og*8 + [0..8) ; max over points ----
    {
        float accA[8], accB[8];
        #pragma unroll
        for (int r = 0; r < 8; r++) { accA[r] = 0.f; accB[r] = 0.f; }
        for (int c = 0; c < 128; c += 4) {
            float4 hA = *(const float4*)&A[ps * 132 + c];
            float4 hB = *(const float4*)&A[(ps + 16) * 132 + c];
            #pragma unroll
            for (int r = 0; r < 8; r++) {
                float4 wv = *(const float4*)&W3[(og * 8 + r) * 128 + c];
                accA[r] += hA.x * wv.x + hA.y * wv.y + hA.z * wv.z + hA.w * wv.w;
                accB[r] += hB.x * wv.x + hB.y * wv.y + hB.z * wv.z + hB.w * wv.w;
            }
        }
        // max over this thread's 2 points (pre-affine: s3>0, monotone)
        float m[8];
        #pragma unroll
        for (int r = 0; r < 8; r++) m[r] = fmaxf(accA[r], accB[r]);
        // reduce across ps (16 lanes within each og group)
        #pragma unroll
        for (int off = 1; off < 16; off <<= 1) {
            #pragma unroll
            for (int r = 0; r < 8; r++)
                m[r] = fmaxf(m[r], __shfl_xor(m[r], off));
        }
        if (ps == 0) {
            #pragma unroll
            for (int r = 0; r < 8; r++) {
                int o = og * 8 + r;
                float z = lrelu((m[r] + b3[o]) * s3[o] + t3[o]);
                atomicMax(&bmax[o], enc_f32(z));
            }
        }
    }
    __syncthreads();
    if (t < 128) atomicMax(&gmax[b * 128 + t], bmax[t]);
}

// ---------------------------------------------------------------------------
// K3: head 128 -> 512 (affine+lrelu) -> 1024.  64 blocks (8 batch x 8 chunk).
// ---------------------------------------------------------------------------
__global__ __launch_bounds__(256) void k3_head(
        const uint32_t* __restrict__ gmax,
        const float* __restrict__ W4, const float* __restrict__ b4,
        const float* __restrict__ s4, const float* __restrict__ t4,
        const float* __restrict__ W5, const float* __restrict__ b5,
        float* __restrict__ out)
{
    __shared__ float sIn[128];
    __shared__ float sH4[512];
    const int t = threadIdx.x;
    const int b = blockIdx.x >> 3;
    const int chunk = blockIdx.x & 7;

    if (t < 128) sIn[t] = dec_f32(gmax[b * 128 + t]);
    __syncthreads();

    #pragma unroll
    for (int rep = 0; rep < 2; rep++) {
        int o = t + rep * 256;
        const float4* wr = (const float4*)&W4[(size_t)o * 128];
        float acc = 0.f;
        for (int c4 = 0; c4 < 32; c4++) {
            float4 wv = wr[c4];
            acc += sIn[c4 * 4] * wv.x + sIn[c4 * 4 + 1] * wv.y
                 + sIn[c4 * 4 + 2] * wv.z + sIn[c4 * 4 + 3] * wv.w;
        }
        float z = (acc + b4[o]) * s4[o] + t4[o];
        sH4[o] = lrelu(z);
    }
    __syncthreads();

    if (t < 128) {
        int o = chunk * 128 + t;
        const float4* wr = (const float4*)&W5[(size_t)o * 512];
        float acc = 0.f;
        for (int c4 = 0; c4 < 128; c4++) {
            float4 wv = wr[c4];
            acc += sH4[c4 * 4] * wv.x + sH4[c4 * 4 + 1] * wv.y
                 + sH4[c4 * 4 + 2] * wv.z + sH4[c4 * 4 + 3] * wv.w;
        }
        out[(size_t)b * 1024 + o] = acc + b5[o];
    }
}

// ---------------------------------------------------------------------------
extern "C" void kernel_launch(void* const* d_in, const int* in_sizes, int n_in,
                              void* d_out, int out_size, void* d_ws, size_t ws_size,
                              hipStream_t stream) {
    (void)in_sizes; (void)n_in; (void)out_size; (void)ws_size;
    const float* x  = (const float*)d_in[0];
    const float* W0 = (const float*)d_in[1];
    const float* b0 = (const float*)d_in[2];
    const float* s0 = (const float*)d_in[3];
    const float* t0 = (const float*)d_in[4];
    const float* W1 = (const float*)d_in[5];
    const float* b1 = (const float*)d_in[6];
    const float* s1 = (const float*)d_in[7];
    const float* t1 = (const float*)d_in[8];
    const float* W2 = (const float*)d_in[9];
    const float* b2 = (const float*)d_in[10];
    const float* s2 = (const float*)d_in[11];
    const float* t2 = (const float*)d_in[12];
    const float* W3 = (const float*)d_in[13];
    const float* b3 = (const float*)d_in[14];
    const float* s3 = (const float*)d_in[15];
    const float* t3 = (const float*)d_in[16];
    const float* W4 = (const float*)d_in[17];
    const float* b4 = (const float*)d_in[18];
    const float* s4 = (const float*)d_in[19];
    const float* t4 = (const float*)d_in[20];
    const float* W5 = (const float*)d_in[21];
    const float* b5 = (const float*)d_in[22];

    float* H0 = (float*)d_ws;                                  // [8][4096][64] f32 = 8 MB
    uint32_t* gmax = (uint32_t*)((char*)d_ws + (size_t)NB * NPTS * 64 * 4);  // [8][128] u32

    hipMemsetAsync(gmax, 0, NB * 128 * sizeof(uint32_t), stream);  // enc(-inf) floor

    k1_knn_edge<<<dim3(512), dim3(1024), 0, stream>>>(x, W0, b0, s0, t0, H0);
    k2_mlp<<<dim3(1024), dim3(256), 0, stream>>>(H0, W1, b1, s1, t1,
                                                 W2, b2, s2, t2,
                                                 W3, b3, s3, t3, gmax);
    k3_head<<<dim3(64), dim3(256), 0, stream>>>(gmax, W4, b4, s4, t4, W5, b5,
                                                (float*)d_out);
}

// Round 4
// 257.802 us; speedup vs baseline: 1.0052x; 1.0052x over previous
//
#include <hip/hip_runtime.h>
#include <hip/hip_bf16.h>
#include <cstdint>

#define NPTS 4096
#define NB 8
#define KNN 20

__device__ __forceinline__ float lrelu(float x) { return x >= 0.0f ? x : 0.2f * x; }

// monotone float<->uint mapping for atomicMax on floats
__device__ __forceinline__ uint32_t enc_f32(float f) {
    uint32_t u = __float_as_uint(f);
    return (u & 0x80000000u) ? ~u : (u | 0x80000000u);
}
__device__ __forceinline__ float dec_f32(uint32_t u) {
    return (u & 0x80000000u) ? __uint_as_float(u ^ 0x80000000u) : __uint_as_float(~u);
}

// wave64 max-reduce via DPP (row_shr 1/2/4/8 + row_bcast 15/31), result
// broadcast from lane 63 through an SGPR.  2 VALU per stage, no LDS pipe.
__device__ __forceinline__ float wave_max64(float v) {
    int o;
    o = __builtin_amdgcn_update_dpp(__float_as_int(v), __float_as_int(v), 0x111, 0xf, 0xf, false);
    v = fmaxf(v, __int_as_float(o));
    o = __builtin_amdgcn_update_dpp(__float_as_int(v), __float_as_int(v), 0x112, 0xf, 0xf, false);
    v = fmaxf(v, __int_as_float(o));
    o = __builtin_amdgcn_update_dpp(__float_as_int(v), __float_as_int(v), 0x114, 0xf, 0xf, false);
    v = fmaxf(v, __int_as_float(o));
    o = __builtin_amdgcn_update_dpp(__float_as_int(v), __float_as_int(v), 0x118, 0xf, 0xf, false);
    v = fmaxf(v, __int_as_float(o));
    o = __builtin_amdgcn_update_dpp(__float_as_int(v), __float_as_int(v), 0x142, 0xa, 0xf, false);
    v = fmaxf(v, __int_as_float(o));
    o = __builtin_amdgcn_update_dpp(__float_as_int(v), __float_as_int(v), 0x143, 0xc, 0xf, false);
    v = fmaxf(v, __int_as_float(o));
    return __int_as_float(__builtin_amdgcn_readlane(__float_as_int(v), 63));
}

// ---------------------------------------------------------------------------
// K1: fused kNN (top-20 smallest sq-dist, ties -> smaller index) + EdgeConv
//     (6->64) + max over k.  512-thread blocks (no spill: 128-VGPR budget),
//     per-lane top-3, DPP wave-argmax merge.  4 rows per wave interleaved.
// ---------------------------------------------------------------------------
__global__ __launch_bounds__(512, 4) void k1_knn_edge(
        const float* __restrict__ x,
        const float* __restrict__ W0, const float* __restrict__ b0,
        const float* __restrict__ s0, const float* __restrict__ t0,
        float* __restrict__ H0)
{
    __shared__ float4 pts[NPTS];          // x,y,z,xx   (64 KB)
    __shared__ float sW0[64 * 6];
    __shared__ float sB[64], sS[64], sT[64];

    const int blk = blockIdx.x;
    const int b = blk >> 7;               // 128 blocks per batch
    const int rowbase = (blk & 127) << 5; // 32 rows per block
    const int t = threadIdx.x;
    const int lane = t & 63;
    const int w = t >> 6;                 // wave 0..7

    const float* xb = x + (size_t)b * (NPTS * 3);
    for (int i = t; i < NPTS; i += 512) {
        float x0 = xb[3 * i], x1 = xb[3 * i + 1], x2 = xb[3 * i + 2];
        // xx exactly as reference: (x0*x0 + x1*x1) + x2*x2, no fma
        float xx = __fadd_rn(__fadd_rn(__fmul_rn(x0, x0), __fmul_rn(x1, x1)),
                             __fmul_rn(x2, x2));
        pts[i] = make_float4(x0, x1, x2, xx);
    }
    if (t < 64) {
        #pragma unroll
        for (int c = 0; c < 6; c++) sW0[t * 6 + c] = W0[t * 6 + c];
        sB[t] = b0[t]; sS[t] = s0[t]; sT[t] = t0[t];
    }
    __syncthreads();

    const int r0 = rowbase + w * 4;

    // per-lane sorted top-3 (descending s; ties keep earlier index)
    float l0s[4], l1s[4], l2s[4];
    int   l0i[4], l1i[4], l2i[4];
    #pragma unroll
    for (int rr = 0; rr < 4; rr++) {
        l0s[rr] = l1s[rr] = l2s[rr] = -INFINITY;
        l0i[rr] = l1i[rr] = l2i[rr] = 0x7FFFFFFF;
    }

    // ---- scan (q held in registers only in this scope) ----
    {
        float4 q[4];
        #pragma unroll
        for (int rr = 0; rr < 4; rr++) q[rr] = pts[r0 + rr];

        #pragma unroll 4
        for (int j = 0; j < 64; j++) {
            const int m = (j << 6) | lane;
            const float4 p = pts[m];
            #pragma unroll
            for (int rr = 0; rr < 4; rr++) {
                float dot = __fadd_rn(__fadd_rn(__fmul_rn(q[rr].x, p.x),
                                                __fmul_rn(q[rr].y, p.y)),
                                      __fmul_rn(q[rr].z, p.z));
                float inner = __fmul_rn(-2.0f, dot);
                float s = __fsub_rn(__fsub_rn(-q[rr].w, inner), p.w);
                bool g0 = s > l0s[rr], g1 = s > l1s[rr], g2 = s > l2s[rr];
                l2s[rr] = fmaxf(fminf(s, l1s[rr]), l2s[rr]);
                l2i[rr] = g1 ? l1i[rr] : (g2 ? m : l2i[rr]);
                l1s[rr] = fmaxf(fminf(s, l0s[rr]), l1s[rr]);
                l1i[rr] = g0 ? l0i[rr] : (g1 ? m : l1i[rr]);
                l0s[rr] = fmaxf(s, l0s[rr]);
                l0i[rr] = g0 ? m : l0i[rr];
            }
        }
    }

    // weights for the consume phase
    const float wa0 = sW0[lane * 6 + 0], wa1 = sW0[lane * 6 + 1], wa2 = sW0[lane * 6 + 2];

    // ---- merge: 20 rounds of wave argmax (DPP), 4 rows interleaved ----
    float mmax[4];
    int cnt[4];
    #pragma unroll
    for (int rr = 0; rr < 4; rr++) { mmax[rr] = -INFINITY; cnt[rr] = 0; }

    for (int rd = 0; rd < KNN; rd++) {
        float bs[4];
        #pragma unroll
        for (int rr = 0; rr < 4; rr++) bs[rr] = wave_max64(l0s[rr]);

        int bi[4];
        #pragma unroll
        for (int rr = 0; rr < 4; rr++) {
            unsigned long long mask = __ballot(l0s[rr] == bs[rr]);
            if (__popcll(mask) == 1) {
                int owner = __ffsll(mask) - 1;
                bi[rr] = __builtin_amdgcn_readlane(l0i[rr], owner);
            } else {
                // exact index tie-break among tied heads (rare)
                int cand = (l0s[rr] == bs[rr]) ? l0i[rr] : 0x7FFFFFFF;
                #pragma unroll
                for (int off = 32; off >= 1; off >>= 1)
                    cand = min(cand, __shfl_xor(cand, off));
                bi[rr] = cand;
            }
        }
        #pragma unroll
        for (int rr = 0; rr < 4; rr++) {
            const float4 p = pts[bi[rr]];
            float dotp = wa0 * p.x + wa1 * p.y + wa2 * p.z;
            mmax[rr] = fmaxf(mmax[rr], dotp);
            bool own = (l0s[rr] == bs[rr]) && (l0i[rr] == bi[rr]);
            cnt[rr] += own ? 1 : 0;
            l0s[rr] = own ? l1s[rr] : l0s[rr]; l0i[rr] = own ? l1i[rr] : l0i[rr];
            l1s[rr] = own ? l2s[rr] : l1s[rr]; l1i[rr] = own ? l2i[rr] : l1i[rr];
            l2s[rr] = own ? -INFINITY : l2s[rr];
            bool flag = own && (cnt[rr] == 3);   // lane exhausted its top-3
            if (__any(flag)) {
                // cold path (~0.2/row): refill head with true next-best
                const float4 qq = pts[r0 + rr];
                const float ps = bs[rr]; const int pm = bi[rr];
                float ns = -INFINITY; int ni = 0x7FFFFFFF;
                for (int j = 0; j < 64; j++) {
                    const int m = (j << 6) | lane;
                    const float4 p2 = pts[m];
                    float dot2 = __fadd_rn(__fadd_rn(__fmul_rn(qq.x, p2.x),
                                                     __fmul_rn(qq.y, p2.y)),
                                           __fmul_rn(qq.z, p2.z));
                    float s2 = __fsub_rn(__fsub_rn(-qq.w, __fmul_rn(-2.0f, dot2)), p2.w);
                    bool worse = (s2 < ps) || (s2 == ps && m > pm);
                    bool bett  = (s2 > ns) || (s2 == ns && m < ni);
                    if (worse && bett) { ns = s2; ni = m; }
                }
                if (flag) { l0s[rr] = ns; l0i[rr] = ni; cnt[rr] = 2; }
            }
        }
    }

    // conv = max_k(W0a.p_k) + (W0b-W0a).q ; (conv+b)*s+t ; lrelu.
    // s0>0 and lrelu monotone => max commutes past affine+activation.
    const float wd0 = sW0[lane * 6 + 3] - wa0;
    const float wd1 = sW0[lane * 6 + 4] - wa1;
    const float wd2 = sW0[lane * 6 + 5] - wa2;
    #pragma unroll
    for (int rr = 0; rr < 4; rr++) {
        const float4 q = pts[r0 + rr];
        float cterm = wd0 * q.x + wd1 * q.y + wd2 * q.z;
        float z = (mmax[rr] + cterm + sB[lane]) * sS[lane] + sT[lane];
        H0[((size_t)(b * NPTS) + r0 + rr) * 64 + lane] = lrelu(z);
    }
}

// ---------------------------------------------------------------------------
// K2: pconv chain 64->64->128->128 + max over points.  1024 blocks x 256 thr.
//     Weights straight from global (L2-cached, broadcast across point-slot
//     lanes); only h tiles in LDS (~26 KB).
//     Thread = (ps 0..15, og 0..15); each thread handles pts {ps, ps+16}.
// ---------------------------------------------------------------------------
__global__ __launch_bounds__(256) void k2_mlp(
        const float* __restrict__ H0,
        const float* __restrict__ W1, const float* __restrict__ b1,
        const float* __restrict__ s1, const float* __restrict__ t1,
        const float* __restrict__ W2, const float* __restrict__ b2,
        const float* __restrict__ s2, const float* __restrict__ t2,
        const float* __restrict__ W3, const float* __restrict__ b3,
        const float* __restrict__ s3, const float* __restrict__ t3,
        uint32_t* __restrict__ gmax)
{
    __shared__ float A[32 * 132];     // h0 (64c) then aliased h2 (128c), stride 132
    __shared__ float h1[32 * 68];     // stride 68
    __shared__ uint32_t bmax[128];

    const int t = threadIdx.x;
    const int blk = blockIdx.x;
    const int b = blk >> 7;               // 128 blocks per batch
    const int pbase = (blk & 127) * 32;   // 32 points per block

    const int ps = t & 15;
    const int og = t >> 4;

    // stage h0 tile [32 pts][64 ch] -> A[p][c] (stride 132)
    {
        const float4* src = (const float4*)&H0[((size_t)(b * NPTS) + pbase) * 64];
        #pragma unroll
        for (int k = 0; k < 2; k++) {
            int i4 = t * 2 + k;           // 512 float4s total
            int p = i4 >> 4, c = (i4 & 15) * 4;
            *(float4*)&A[p * 132 + c] = src[i4];
        }
    }
    if (t < 128) bmax[t] = 0u;
    __syncthreads();

    // ---- L1: 64 -> 64 ; thread outs o = og*4 + [0..4) for pts ps, ps+16 ----
    {
        float accA[4] = {0.f, 0.f, 0.f, 0.f};
        float accB[4] = {0.f, 0.f, 0.f, 0.f};
        for (int c = 0; c < 64; c += 4) {
            float4 hA = *(const float4*)&A[ps * 132 + c];
            float4 hB = *(const float4*)&A[(ps + 16) * 132 + c];
            #pragma unroll
            for (int r = 0; r < 4; r++) {
                float4 wv = *(const float4*)&W1[(og * 4 + r) * 64 + c];
                accA[r] += hA.x * wv.x + hA.y * wv.y + hA.z * wv.z + hA.w * wv.w;
                accB[r] += hB.x * wv.x + hB.y * wv.y + hB.z * wv.z + hB.w * wv.w;
            }
        }
        float4 oA, oB;
        float* pA = (float*)&oA; float* pB = (float*)&oB;
        #pragma unroll
        for (int r = 0; r < 4; r++) {
            int o = og * 4 + r;
            float bb = b1[o], ss = s1[o], tt = t1[o];
            pA[r] = lrelu((accA[r] + bb) * ss + tt);
            pB[r] = lrelu((accB[r] + bb) * ss + tt);
        }
        *(float4*)&h1[ps * 68 + og * 4] = oA;
        *(float4*)&h1[(ps + 16) * 68 + og * 4] = oB;
    }
    __syncthreads();

    // ---- L2: 64 -> 128 ; thread outs o = og*8 + [0..8) ; writes h2 into A ----
    {
        float accA[8], accB[8];
        #pragma unroll
        for (int r = 0; r < 8; r++) { accA[r] = 0.f; accB[r] = 0.f; }
        for (int c = 0; c < 64; c += 4) {
            float4 hA = *(const float4*)&h1[ps * 68 + c];
            float4 hB = *(const float4*)&h1[(ps + 16) * 68 + c];
            #pragma unroll
            for (int r = 0; r < 8; r++) {
                float4 wv = *(const float4*)&W2[(og * 8 + r) * 64 + c];
                accA[r] += hA.x * wv.x + hA.y * wv.y + hA.z * wv.z + hA.w * wv.w;
                accB[r] += hB.x * wv.x + hB.y * wv.y + hB.z * wv.z + hB.w * wv.w;
            }
        }
        float4 oA[2], oB[2];
        float* pA = (float*)oA; float* pB = (float*)oB;
        #pragma unroll
        for (int r = 0; r < 8; r++) {
            int o = og * 8 + r;
            float bb = b2[o], ss = s2[o], tt = t2[o];
            pA[r] = lrelu((accA[r] + bb) * ss + tt);
            pB[r] = lrelu((accB[r] + bb) * ss + tt);
        }
        __syncthreads();   // everyone done reading A (h0) before overwriting
        *(float4*)&A[ps * 132 + og * 8]            = oA[0];
        *(float4*)&A[ps * 132 + og * 8 + 4]        = oA[1];
        *(float4*)&A[(ps + 16) * 132 + og * 8]     = oB[0];
        *(float4*)&A[(ps + 16) * 132 + og * 8 + 4] = oB[1];
    }
    __syncthreads();

    // ---- L3: 128 -> 128 ; thread outs o = og*8 + [0..8) ; max over points ----
    {
        float accA[8], accB[8];
        #pragma unroll
        for (int r = 0; r < 8; r++) { accA[r] = 0.f; accB[r] = 0.f; }
        for (int c = 0; c < 128; c += 4) {
            float4 hA = *(const float4*)&A[ps * 132 + c];
            float4 hB = *(const float4*)&A[(ps + 16) * 132 + c];
            #pragma unroll
            for (int r = 0; r < 8; r++) {
                float4 wv = *(const float4*)&W3[(og * 8 + r) * 128 + c];
                accA[r] += hA.x * wv.x + hA.y * wv.y + hA.z * wv.z + hA.w * wv.w;
                accB[r] += hB.x * wv.x + hB.y * wv.y + hB.z * wv.z + hB.w * wv.w;
            }
        }
        // max over this thread's 2 points (pre-affine: s3>0, monotone)
        float m[8];
        #pragma unroll
        for (int r = 0; r < 8; r++) m[r] = fmaxf(accA[r], accB[r]);
        // reduce across ps (16 lanes within each og group)
        #pragma unroll
        for (int off = 1; off < 16; off <<= 1) {
            #pragma unroll
            for (int r = 0; r < 8; r++)
                m[r] = fmaxf(m[r], __shfl_xor(m[r], off));
        }
        if (ps == 0) {
            #pragma unroll
            for (int r = 0; r < 8; r++) {
                int o = og * 8 + r;
                float z = lrelu((m[r] + b3[o]) * s3[o] + t3[o]);
                atomicMax(&bmax[o], enc_f32(z));
            }
        }
    }
    __syncthreads();
    if (t < 128) atomicMax(&gmax[b * 128 + t], bmax[t]);
}

// ---------------------------------------------------------------------------
// K3: head 128 -> 512 (affine+lrelu) -> 1024.  64 blocks (8 batch x 8 chunk).
// ---------------------------------------------------------------------------
__global__ __launch_bounds__(256) void k3_head(
        const uint32_t* __restrict__ gmax,
        const float* __restrict__ W4, const float* __restrict__ b4,
        const float* __restrict__ s4, const float* __restrict__ t4,
        const float* __restrict__ W5, const float* __restrict__ b5,
        float* __restrict__ out)
{
    __shared__ float sIn[128];
    __shared__ float sH4[512];
    const int t = threadIdx.x;
    const int b = blockIdx.x >> 3;
    const int chunk = blockIdx.x & 7;

    if (t < 128) sIn[t] = dec_f32(gmax[b * 128 + t]);
    __syncthreads();

    #pragma unroll
    for (int rep = 0; rep < 2; rep++) {
        int o = t + rep * 256;
        const float4* wr = (const float4*)&W4[(size_t)o * 128];
        float acc = 0.f;
        for (int c4 = 0; c4 < 32; c4++) {
            float4 wv = wr[c4];
            acc += sIn[c4 * 4] * wv.x + sIn[c4 * 4 + 1] * wv.y
                 + sIn[c4 * 4 + 2] * wv.z + sIn[c4 * 4 + 3] * wv.w;
        }
        float z = (acc + b4[o]) * s4[o] + t4[o];
        sH4[o] = lrelu(z);
    }
    __syncthreads();

    if (t < 128) {
        int o = chunk * 128 + t;
        const float4* wr = (const float4*)&W5[(size_t)o * 512];
        float acc = 0.f;
        for (int c4 = 0; c4 < 128; c4++) {
            float4 wv = wr[c4];
            acc += sH4[c4 * 4] * wv.x + sH4[c4 * 4 + 1] * wv.y
                 + sH4[c4 * 4 + 2] * wv.z + sH4[c4 * 4 + 3] * wv.w;
        }
        out[(size_t)b * 1024 + o] = acc + b5[o];
    }
}

// ---------------------------------------------------------------------------
extern "C" void kernel_launch(void* const* d_in, const int* in_sizes, int n_in,
                              void* d_out, int out_size, void* d_ws, size_t ws_size,
                              hipStream_t stream) {
    (void)in_sizes; (void)n_in; (void)out_size; (void)ws_size;
    const float* x  = (const float*)d_in[0];
    const float* W0 = (const float*)d_in[1];
    const float* b0 = (const float*)d_in[2];
    const float* s0 = (const float*)d_in[3];
    const float* t0 = (const float*)d_in[4];
    const float* W1 = (const float*)d_in[5];
    const float* b1 = (const float*)d_in[6];
    const float* s1 = (const float*)d_in[7];
    const float* t1 = (const float*)d_in[8];
    const float* W2 = (const float*)d_in[9];
    const float* b2 = (const float*)d_in[10];
    const float* s2 = (const float*)d_in[11];
    const float* t2 = (const float*)d_in[12];
    const float* W3 = (const float*)d_in[13];
    const float* b3 = (const float*)d_in[14];
    const float* s3 = (const float*)d_in[15];
    const float* t3 = (const float*)d_in[16];
    const float* W4 = (const float*)d_in[17];
    const float* b4 = (const float*)d_in[18];
    const float* s4 = (const float*)d_in[19];
    const float* t4 = (const float*)d_in[20];
    const float* W5 = (const float*)d_in[21];
    const float* b5 = (const float*)d_in[22];

    float* H0 = (float*)d_ws;                                  // [8][4096][64] f32 = 8 MB
    uint32_t* gmax = (uint32_t*)((char*)d_ws + (size_t)NB * NPTS * 64 * 4);  // [8][128] u32

    hipMemsetAsync(gmax, 0, NB * 128 * sizeof(uint32_t), stream);  // enc(-inf) floor

    k1_knn_edge<<<dim3(1024), dim3(512), 0, stream>>>(x, W0, b0, s0, t0, H0);
    k2_mlp<<<dim3(1024), dim3(256), 0, stream>>>(H0, W1, b1, s1, t1,
                                                 W2, b2, s2, t2,
                                                 W3, b3, s3, t3, gmax);
    k3_head<<<dim3(64), dim3(256), 0, stream>>>(gmax, W4, b4, s4, t4, W5, b5,
                                                (float*)d_out);
}

// Round 6
// 202.146 us; speedup vs baseline: 1.2820x; 1.2753x over previous
//
#include <hip/hip_runtime.h>
#include <hip/hip_bf16.h>
#include <cstdint>

#define NPTS 4096
#define NB 8
#define KNN 20
#define CAP 32          // compacted neighbor-list capacity (>= 20 + tie slack)

__device__ __forceinline__ float lrelu(float x) { return x >= 0.0f ? x : 0.2f * x; }

// monotone float<->uint mapping for atomicMax on floats
__device__ __forceinline__ uint32_t enc_f32(float f) {
    uint32_t u = __float_as_uint(f);
    return (u & 0x80000000u) ? ~u : (u | 0x80000000u);
}
__device__ __forceinline__ float dec_f32(uint32_t u) {
    return (u & 0x80000000u) ? __uint_as_float(u ^ 0x80000000u) : __uint_as_float(~u);
}

// wave64 max-reduce via DPP (row_shr 1/2/4/8 + row_bcast 15/31), result
// broadcast from lane 63 through an SGPR (proved correct in R4).
__device__ __forceinline__ float wave_max64(float v) {
    int o;
    o = __builtin_amdgcn_update_dpp(__float_as_int(v), __float_as_int(v), 0x111, 0xf, 0xf, false);
    v = fmaxf(v, __int_as_float(o));
    o = __builtin_amdgcn_update_dpp(__float_as_int(v), __float_as_int(v), 0x112, 0xf, 0xf, false);
    v = fmaxf(v, __int_as_float(o));
    o = __builtin_amdgcn_update_dpp(__float_as_int(v), __float_as_int(v), 0x114, 0xf, 0xf, false);
    v = fmaxf(v, __int_as_float(o));
    o = __builtin_amdgcn_update_dpp(__float_as_int(v), __float_as_int(v), 0x118, 0xf, 0xf, false);
    v = fmaxf(v, __int_as_float(o));
    o = __builtin_amdgcn_update_dpp(__float_as_int(v), __float_as_int(v), 0x142, 0xa, 0xf, false);
    v = fmaxf(v, __int_as_float(o));
    o = __builtin_amdgcn_update_dpp(__float_as_int(v), __float_as_int(v), 0x143, 0xc, 0xf, false);
    v = fmaxf(v, __int_as_float(o));
    return __int_as_float(__builtin_amdgcn_readlane(__float_as_int(v), 63));
}

// selection key: u = 2*(q.p) - |p|^2  (monotone in neg_sq_dist for fixed q)
__device__ __forceinline__ float ukey(float qx, float qy, float qz, float4 p) {
    float dot = fmaf(qz, p.z, fmaf(qy, p.y, qx * p.x));
    return fmaf(2.0f, dot, -p.w);
}

// ---------------------------------------------------------------------------
// K1: fused kNN (top-20, ties -> smaller index) + EdgeConv (6->64) + max-k.
//     512-thr blocks, 4 rows per wave.  Three phases:
//       P1: per-lane top-3 u-VALUES (no indices) -- cheap fmax/fmin chain
//       P2: 20 rounds of value-only DPP wave-max -> theta (20th value)
//       P3: theta rescan -> compact hit indices to LDS -> consume
// ---------------------------------------------------------------------------
__global__ __launch_bounds__(512, 4) void k1_knn_edge(
        const float* __restrict__ x,
        const float* __restrict__ W0, const float* __restrict__ b0,
        const float* __restrict__ s0, const float* __restrict__ t0,
        float* __restrict__ H0)
{
    __shared__ float4 pts[NPTS];          // x,y,z,xx   (64 KB)
    __shared__ int    lists[8][4][CAP];   // per-wave per-row hit indices (4 KB)
    __shared__ int    lcnt[8][4];
    __shared__ float  sW0[64 * 6];
    __shared__ float  sB[64], sS[64], sT[64];

    const int blk = blockIdx.x;
    const int b = blk >> 7;               // 128 blocks per batch
    const int rowbase = (blk & 127) << 5; // 32 rows per block
    const int t = threadIdx.x;
    const int lane = t & 63;
    const int w = t >> 6;                 // wave 0..7

    const float* xb = x + (size_t)b * (NPTS * 3);
    for (int i = t; i < NPTS; i += 512) {
        float x0 = xb[3 * i], x1 = xb[3 * i + 1], x2 = xb[3 * i + 2];
        float xx = __fadd_rn(__fadd_rn(__fmul_rn(x0, x0), __fmul_rn(x1, x1)),
                             __fmul_rn(x2, x2));
        pts[i] = make_float4(x0, x1, x2, xx);
    }
    if (t < 64) {
        #pragma unroll
        for (int c = 0; c < 6; c++) sW0[t * 6 + c] = W0[t * 6 + c];
        sB[t] = b0[t]; sS[t] = s0[t]; sT[t] = t0[t];
    }
    __syncthreads();

    const int r0 = rowbase + w * 4;

    float qx[4], qy[4], qz[4];
    #pragma unroll
    for (int rr = 0; rr < 4; rr++) {
        float4 q = pts[r0 + rr];
        qx[rr] = q.x; qy[rr] = q.y; qz[rr] = q.z;
    }

    // ---- P1: per-lane top-3 values ----
    float l0s[4], l1s[4], l2s[4];
    #pragma unroll
    for (int rr = 0; rr < 4; rr++) l0s[rr] = l1s[rr] = l2s[rr] = -INFINITY;

    #pragma unroll 4
    for (int j = 0; j < 64; j++) {
        const float4 p = pts[(j << 6) | lane];
        #pragma unroll
        for (int rr = 0; rr < 4; rr++) {
            float u = ukey(qx[rr], qy[rr], qz[rr], p);
            float m1 = fminf(u, l0s[rr]);
            float m2 = fminf(u, l1s[rr]);
            l0s[rr] = fmaxf(u, l0s[rr]);
            l1s[rr] = fmaxf(m1, l1s[rr]);
            l2s[rr] = fmaxf(m2, l2s[rr]);
        }
    }

    // ---- P2: 20 extraction rounds -> theta per row ----
    float th[4];
    int cnt[4] = {0, 0, 0, 0};
    for (int rd = 0; rd < KNN; rd++) {
        bool flag[4];
        float bsv[4];
        #pragma unroll
        for (int rr = 0; rr < 4; rr++) {
            float bs = wave_max64(l0s[rr]);
            bsv[rr] = bs;
            if (rd == KNN - 1) th[rr] = bs;
            unsigned long long mask = __ballot(l0s[rr] == bs);
            int owner = __ffsll(mask) - 1;        // uniform (SALU)
            bool own = (lane == owner);
            cnt[rr] += own ? 1 : 0;
            l0s[rr] = own ? l1s[rr] : l0s[rr];
            l1s[rr] = own ? l2s[rr] : l1s[rr];
            l2s[rr] = own ? -INFINITY : l2s[rr];
            flag[rr] = own && (cnt[rr] == 3);
        }
        if (rd < KNN - 1 && __any(flag[0] | flag[1] | flag[2] | flag[3])) {
            // cold refill: lane exhausted its 3 values -> next-best below bs
            #pragma unroll
            for (int rr = 0; rr < 4; rr++) {
                if (__any(flag[rr])) {
                    float ns = -INFINITY;
                    const float bs = bsv[rr];
                    for (int j = 0; j < 64; j++) {
                        const float4 p = pts[(j << 6) | lane];
                        float u = ukey(qx[rr], qy[rr], qz[rr], p);
                        ns = fmaxf(ns, (u < bs) ? u : -INFINITY);
                    }
                    if (flag[rr]) { l0s[rr] = ns; cnt[rr] = 2; }
                }
            }
        }
    }

    // ---- P3a: theta rescan -> compact hit indices ----
    if (lane < 4) lcnt[w][lane] = 0;
    #pragma unroll 2
    for (int j = 0; j < 64; j++) {
        const int m = (j << 6) | lane;
        const float4 p = pts[m];
        #pragma unroll
        for (int rr = 0; rr < 4; rr++) {
            float u = ukey(qx[rr], qy[rr], qz[rr], p);
            if (u >= th[rr]) {
                int slot = atomicAdd(&lcnt[w][rr], 1);
                if (slot < CAP) lists[w][rr][slot] = m;
            }
        }
    }

    // ---- P3b: exact tie cleanup (cold: only when >20 qualify) ----
    #pragma unroll
    for (int rr = 0; rr < 4; rr++) {
        int n = min(lcnt[w][rr], CAP);
        if (n > KNN) {                      // wave-uniform
            if (lane == 0) {
                for (int d = 0; d < n - KNN; d++) {
                    // drop the largest-index entry whose u == theta
                    int bi = -1, bpos = -1;
                    for (int e = 0; e < n; e++) {
                        int m = lists[w][rr][e];
                        if (m < 0) continue;
                        float u = ukey(qx[rr], qy[rr], qz[rr], pts[m]);
                        if (u == th[rr] && m > bi) { bi = m; bpos = e; }
                    }
                    if (bpos >= 0) lists[w][rr][bpos] = -1;
                }
            }
        }
    }

    // ---- P3c: consume -- per-channel max over selected neighbors ----
    const float wa0 = sW0[lane * 6 + 0], wa1 = sW0[lane * 6 + 1], wa2 = sW0[lane * 6 + 2];
    const float wd0 = sW0[lane * 6 + 3] - wa0;
    const float wd1 = sW0[lane * 6 + 4] - wa1;
    const float wd2 = sW0[lane * 6 + 5] - wa2;

    #pragma unroll
    for (int rr = 0; rr < 4; rr++) {
        int n = min(lcnt[w][rr], CAP);
        float mm = -INFINITY;
        for (int e = 0; e < n; e++) {
            int m = lists[w][rr][e];     // uniform -> broadcast read
            if (m < 0) continue;
            float4 p = pts[m];
            float dotp = fmaf(wa2, p.z, fmaf(wa1, p.y, wa0 * p.x));
            mm = fmaxf(mm, dotp);
        }
        // conv = max_k(W0a.p_k) + (W0b-W0a).q ; (conv+b)*s+t ; lrelu.
        float cterm = fmaf(wd2, qz[rr], fmaf(wd1, qy[rr], wd0 * qx[rr]));
        float z = (mm + cterm + sB[lane]) * sS[lane] + sT[lane];
        H0[((size_t)(b * NPTS) + r0 + rr) * 64 + lane] = lrelu(z);
    }
}

// ---------------------------------------------------------------------------
// K2: pconv chain 64->64->128->128 + max over points.  1024 blocks x 256 thr.
//     Weights from global (L2-cached, lanes in an og-group share addresses);
//     only h tiles in LDS (~26 KB).
// ---------------------------------------------------------------------------
__global__ __launch_bounds__(256) void k2_mlp(
        const float* __restrict__ H0,
        const float* __restrict__ W1, const float* __restrict__ b1,
        const float* __restrict__ s1, const float* __restrict__ t1,
        const float* __restrict__ W2, const float* __restrict__ b2,
        const float* __restrict__ s2, const float* __restrict__ t2,
        const float* __restrict__ W3, const float* __restrict__ b3,
        const float* __restrict__ s3, const float* __restrict__ t3,
        uint32_t* __restrict__ gmax)
{
    __shared__ float A[32 * 132];     // h0 (64c) then aliased h2 (128c), stride 132
    __shared__ float h1[32 * 68];     // stride 68
    __shared__ uint32_t bmax[128];

    const int t = threadIdx.x;
    const int blk = blockIdx.x;
    const int b = blk >> 7;               // 128 blocks per batch
    const int pbase = (blk & 127) * 32;   // 32 points per block

    const int ps = t & 15;
    const int og = t >> 4;

    {
        const float4* src = (const float4*)&H0[((size_t)(b * NPTS) + pbase) * 64];
        #pragma unroll
        for (int k = 0; k < 2; k++) {
            int i4 = t * 2 + k;
            int p = i4 >> 4, c = (i4 & 15) * 4;
            *(float4*)&A[p * 132 + c] = src[i4];
        }
    }
    if (t < 128) bmax[t] = 0u;
    __syncthreads();

    // ---- L1: 64 -> 64 ----
    {
        float accA[4] = {0.f, 0.f, 0.f, 0.f};
        float accB[4] = {0.f, 0.f, 0.f, 0.f};
        for (int c = 0; c < 64; c += 4) {
            float4 hA = *(const float4*)&A[ps * 132 + c];
            float4 hB = *(const float4*)&A[(ps + 16) * 132 + c];
            #pragma unroll
            for (int r = 0; r < 4; r++) {
                float4 wv = *(const float4*)&W1[(og * 4 + r) * 64 + c];
                accA[r] += hA.x * wv.x + hA.y * wv.y + hA.z * wv.z + hA.w * wv.w;
                accB[r] += hB.x * wv.x + hB.y * wv.y + hB.z * wv.z + hB.w * wv.w;
            }
        }
        float4 oA, oB;
        float* pA = (float*)&oA; float* pB = (float*)&oB;
        #pragma unroll
        for (int r = 0; r < 4; r++) {
            int o = og * 4 + r;
            float bb = b1[o], ss = s1[o], tt = t1[o];
            pA[r] = lrelu((accA[r] + bb) * ss + tt);
            pB[r] = lrelu((accB[r] + bb) * ss + tt);
        }
        *(float4*)&h1[ps * 68 + og * 4] = oA;
        *(float4*)&h1[(ps + 16) * 68 + og * 4] = oB;
    }
    __syncthreads();

    // ---- L2: 64 -> 128 ----
    {
        float accA[8], accB[8];
        #pragma unroll
        for (int r = 0; r < 8; r++) { accA[r] = 0.f; accB[r] = 0.f; }
        for (int c = 0; c < 64; c += 4) {
            float4 hA = *(const float4*)&h1[ps * 68 + c];
            float4 hB = *(const float4*)&h1[(ps + 16) * 68 + c];
            #pragma unroll
            for (int r = 0; r < 8; r++) {
                float4 wv = *(const float4*)&W2[(og * 8 + r) * 64 + c];
                accA[r] += hA.x * wv.x + hA.y * wv.y + hA.z * wv.z + hA.w * wv.w;
                accB[r] += hB.x * wv.x + hB.y * wv.y + hB.z * wv.z + hB.w * wv.w;
            }
        }
        float4 oA[2], oB[2];
        float* pA = (float*)oA; float* pB = (float*)oB;
        #pragma unroll
        for (int r = 0; r < 8; r++) {
            int o = og * 8 + r;
            float bb = b2[o], ss = s2[o], tt = t2[o];
            pA[r] = lrelu((accA[r] + bb) * ss + tt);
            pB[r] = lrelu((accB[r] + bb) * ss + tt);
        }
        __syncthreads();
        *(float4*)&A[ps * 132 + og * 8]            = oA[0];
        *(float4*)&A[ps * 132 + og * 8 + 4]        = oA[1];
        *(float4*)&A[(ps + 16) * 132 + og * 8]     = oB[0];
        *(float4*)&A[(ps + 16) * 132 + og * 8 + 4] = oB[1];
    }
    __syncthreads();

    // ---- L3: 128 -> 128 + max over points ----
    {
        float accA[8], accB[8];
        #pragma unroll
        for (int r = 0; r < 8; r++) { accA[r] = 0.f; accB[r] = 0.f; }
        for (int c = 0; c < 128; c += 4) {
            float4 hA = *(const float4*)&A[ps * 132 + c];
            float4 hB = *(const float4*)&A[(ps + 16) * 132 + c];
            #pragma unroll
            for (int r = 0; r < 8; r++) {
                float4 wv = *(const float4*)&W3[(og * 8 + r) * 128 + c];
                accA[r] += hA.x * wv.x + hA.y * wv.y + hA.z * wv.z + hA.w * wv.w;
                accB[r] += hB.x * wv.x + hB.y * wv.y + hB.z * wv.z + hB.w * wv.w;
            }
        }
        float m[8];
        #pragma unroll
        for (int r = 0; r < 8; r++) m[r] = fmaxf(accA[r], accB[r]);
        #pragma unroll
        for (int off = 1; off < 16; off <<= 1) {
            #pragma unroll
            for (int r = 0; r < 8; r++)
                m[r] = fmaxf(m[r], __shfl_xor(m[r], off));
        }
        if (ps == 0) {
            #pragma unroll
            for (int r = 0; r < 8; r++) {
                int o = og * 8 + r;
                float z = lrelu((m[r] + b3[o]) * s3[o] + t3[o]);
                atomicMax(&bmax[o], enc_f32(z));
            }
        }
    }
    __syncthreads();
    if (t < 128) atomicMax(&gmax[b * 128 + t], bmax[t]);
}

// ---------------------------------------------------------------------------
// K3: head 128 -> 512 (affine+lrelu) -> 1024.  64 blocks (8 batch x 8 chunk).
// ---------------------------------------------------------------------------
__global__ __launch_bounds__(256) void k3_head(
        const uint32_t* __restrict__ gmax,
        const float* __restrict__ W4, const float* __restrict__ b4,
        const float* __restrict__ s4, const float* __restrict__ t4,
        const float* __restrict__ W5, const float* __restrict__ b5,
        float* __restrict__ out)
{
    __shared__ float sIn[128];
    __shared__ float sH4[512];
    const int t = threadIdx.x;
    const int b = blockIdx.x >> 3;
    const int chunk = blockIdx.x & 7;

    if (t < 128) sIn[t] = dec_f32(gmax[b * 128 + t]);
    __syncthreads();

    #pragma unroll
    for (int rep = 0; rep < 2; rep++) {
        int o = t + rep * 256;
        const float4* wr = (const float4*)&W4[(size_t)o * 128];
        float acc = 0.f;
        for (int c4 = 0; c4 < 32; c4++) {
            float4 wv = wr[c4];
            acc += sIn[c4 * 4] * wv.x + sIn[c4 * 4 + 1] * wv.y
                 + sIn[c4 * 4 + 2] * wv.z + sIn[c4 * 4 + 3] * wv.w;
        }
        float z = (acc + b4[o]) * s4[o] + t4[o];
        sH4[o] = lrelu(z);
    }
    __syncthreads();

    if (t < 128) {
        int o = chunk * 128 + t;
        const float4* wr = (const float4*)&W5[(size_t)o * 512];
        float acc = 0.f;
        for (int c4 = 0; c4 < 128; c4++) {
            float4 wv = wr[c4];
            acc += sH4[c4 * 4] * wv.x + sH4[c4 * 4 + 1] * wv.y
                 + sH4[c4 * 4 + 2] * wv.z + sH4[c4 * 4 + 3] * wv.w;
        }
        out[(size_t)b * 1024 + o] = acc + b5[o];
    }
}

// ---------------------------------------------------------------------------
extern "C" void kernel_launch(void* const* d_in, const int* in_sizes, int n_in,
                              void* d_out, int out_size, void* d_ws, size_t ws_size,
                              hipStream_t stream) {
    (void)in_sizes; (void)n_in; (void)out_size; (void)ws_size;
    const float* x  = (const float*)d_in[0];
    const float* W0 = (const float*)d_in[1];
    const float* b0 = (const float*)d_in[2];
    const float* s0 = (const float*)d_in[3];
    const float* t0 = (const float*)d_in[4];
    const float* W1 = (const float*)d_in[5];
    const float* b1 = (const float*)d_in[6];
    const float* s1 = (const float*)d_in[7];
    const float* t1 = (const float*)d_in[8];
    const float* W2 = (const float*)d_in[9];
    const float* b2 = (const float*)d_in[10];
    const float* s2 = (const float*)d_in[11];
    const float* t2 = (const float*)d_in[12];
    const float* W3 = (const float*)d_in[13];
    const float* b3 = (const float*)d_in[14];
    const float* s3 = (const float*)d_in[15];
    const float* t3 = (const float*)d_in[16];
    const float* W4 = (const float*)d_in[17];
    const float* b4 = (const float*)d_in[18];
    const float* s4 = (const float*)d_in[19];
    const float* t4 = (const float*)d_in[20];
    const float* W5 = (const float*)d_in[21];
    const float* b5 = (const float*)d_in[22];

    float* H0 = (float*)d_ws;                                  // [8][4096][64] f32 = 8 MB
    uint32_t* gmax = (uint32_t*)((char*)d_ws + (size_t)NB * NPTS * 64 * 4);  // [8][128] u32

    hipMemsetAsync(gmax, 0, NB * 128 * sizeof(uint32_t), stream);  // enc(-inf) floor

    k1_knn_edge<<<dim3(1024), dim3(512), 0, stream>>>(x, W0, b0, s0, t0, H0);
    k2_mlp<<<dim3(1024), dim3(256), 0, stream>>>(H0, W1, b1, s1, t1,
                                                 W2, b2, s2, t2,
                                                 W3, b3, s3, t3, gmax);
    k3_head<<<dim3(64), dim3(256), 0, stream>>>(gmax, W4, b4, s4, t4, W5, b5,
                                                (float*)d_out);
}

// Round 7
// 182.234 us; speedup vs baseline: 1.4221x; 1.1093x over previous
//
#include <hip/hip_runtime.h>
#include <hip/hip_bf16.h>
#include <cstdint>

#define NPTS 4096
#define TILE 2048
#define NB 8
#define KNN 20
#define CAP 40          // collected-candidate capacity (>= 20 + concentration slack)

__device__ __forceinline__ float lrelu(float x) { return x >= 0.0f ? x : 0.2f * x; }

// monotone float<->uint mapping (order-preserving for all finite floats)
__device__ __forceinline__ uint32_t enc_f32(float f) {
    uint32_t u = __float_as_uint(f);
    return (u & 0x80000000u) ? ~u : (u | 0x80000000u);
}
__device__ __forceinline__ float dec_f32(uint32_t u) {
    return (u & 0x80000000u) ? __uint_as_float(u ^ 0x80000000u) : __uint_as_float(~u);
}

// ---------------------------------------------------------------------------
// K1: fused kNN (top-20 smallest sq-dist, ties -> smaller index) + EdgeConv
//     (6->64) + max over k.  512-thr blocks, 4 rows/wave, 2-tile LDS staging
//     (48 KB total -> 3 blocks/CU).
//     P1: per-lane top-2 u-values (u = 2 q.p - |p|^2, monotone in -dist)
//     P2: radix-ballot select -> theta~ = 20th of the 128 lane-top-2s
//         (theta~ <= true theta, so threshold rescan is sound)
//     P3: rescan collect (value,idx) >= theta~ ; exact rank when n > 20;
//         consume = per-channel max of W0a.p over selected.
// ---------------------------------------------------------------------------
__global__ __launch_bounds__(512, 4) void k1_knn_edge(
        const float* __restrict__ x,
        const float* __restrict__ W0, const float* __restrict__ b0,
        const float* __restrict__ s0, const float* __restrict__ t0,
        float* __restrict__ H0)
{
    __shared__ float4 ptile[TILE];        // (2x, 2y, 2z, -|p|^2)   32 KB
    __shared__ float  cval[8][4][CAP];    // 5 KB
    __shared__ int    cidx[8][4][CAP];    // 5 KB
    __shared__ int    ccnt[8][4];
    __shared__ int    sel[8][4][KNN];     // 2.5 KB
    __shared__ float  sW0[64 * 6];
    __shared__ float  sB[64], sS[64], sT[64];

    const int blk = blockIdx.x;
    const int b = blk >> 7;               // 128 blocks per batch
    const int rowbase = (blk & 127) << 5; // 32 rows per block
    const int t = threadIdx.x;
    const int lane = t & 63;
    const int w = t >> 6;                 // wave 0..7

    const float* xb = x + (size_t)b * (NPTS * 3);

    if (t < 64) {
        #pragma unroll
        for (int c = 0; c < 6; c++) sW0[t * 6 + c] = W0[t * 6 + c];
        sB[t] = b0[t]; sS[t] = s0[t]; sT[t] = t0[t];
    }

    // q for this wave's 4 rows, straight from global (L2/L1-cached)
    const int r0 = rowbase + w * 4;
    float qx[4], qy[4], qz[4];
    #pragma unroll
    for (int rr = 0; rr < 4; rr++) {
        qx[rr] = xb[3 * (r0 + rr) + 0];
        qy[rr] = xb[3 * (r0 + rr) + 1];
        qz[rr] = xb[3 * (r0 + rr) + 2];
    }

#define STAGE_TILE(tl)                                                        \
    for (int i = t; i < TILE; i += 512) {                                     \
        int g = (tl) * TILE + i;                                              \
        float x0 = xb[3 * g], x1 = xb[3 * g + 1], x2 = xb[3 * g + 2];         \
        float pp = __fadd_rn(__fadd_rn(__fmul_rn(x0, x0), __fmul_rn(x1, x1)), \
                             __fmul_rn(x2, x2));                              \
        ptile[i] = make_float4(x0 + x0, x1 + x1, x2 + x2, -pp);               \
    }

    // ---- P1: per-lane top-2 values over 2 tiles ----
    float l0[4], l1[4];
    #pragma unroll
    for (int rr = 0; rr < 4; rr++) { l0[rr] = -INFINITY; l1[rr] = -INFINITY; }

    for (int tl = 0; tl < 2; tl++) {
        __syncthreads();
        STAGE_TILE(tl)
        __syncthreads();
        #pragma unroll 4
        for (int j = 0; j < TILE / 64; j++) {
            const float4 p = ptile[(j << 6) | lane];
            #pragma unroll
            for (int rr = 0; rr < 4; rr++) {
                float u = fmaf(qx[rr], p.x, fmaf(qy[rr], p.y, fmaf(qz[rr], p.z, p.w)));
                float m1 = fminf(u, l0[rr]);
                l0[rr] = fmaxf(u, l0[rr]);
                l1[rr] = fmaxf(m1, l1[rr]);
            }
        }
    }

    // ---- P2: radix-ballot select theta~ (20th largest of lane-top-2s) ----
    uint32_t e0[4], e1[4], pr[4];
    #pragma unroll
    for (int rr = 0; rr < 4; rr++) {
        e0[rr] = enc_f32(l0[rr]);
        e1[rr] = enc_f32(l1[rr]);
        pr[rr] = 0u;
    }
    for (int bit = 31; bit >= 0; bit--) {
        #pragma unroll
        for (int rr = 0; rr < 4; rr++) {
            uint32_t T = pr[rr] | (1u << bit);
            int c = __popcll(__ballot(e0[rr] >= T)) + __popcll(__ballot(e1[rr] >= T));
            if (c >= KNN) pr[rr] = T;     // wave-uniform
        }
    }
    float th[4];
    #pragma unroll
    for (int rr = 0; rr < 4; rr++) th[rr] = dec_f32(pr[rr]);

    // ---- P3a: threshold rescan -> collect (value, index) ----
    if (lane < 4) ccnt[w][lane] = 0;
    for (int tl = 0; tl < 2; tl++) {
        __syncthreads();
        STAGE_TILE(tl)
        __syncthreads();
        #pragma unroll 2
        for (int j = 0; j < TILE / 64; j++) {
            const int ml = (j << 6) | lane;
            const float4 p = ptile[ml];
            #pragma unroll
            for (int rr = 0; rr < 4; rr++) {
                float u = fmaf(qx[rr], p.x, fmaf(qy[rr], p.y, fmaf(qz[rr], p.z, p.w)));
                if (u >= th[rr]) {
                    int s = atomicAdd(&ccnt[w][rr], 1);
                    if (s < CAP) {
                        cval[w][rr][s] = u;
                        cidx[w][rr][s] = tl * TILE + ml;
                    }
                }
            }
        }
    }
    __syncthreads();   // safety: ensure collect LDS fully visible before rank

    // ---- P3b: exact top-20 by (value desc, idx asc) when n > 20 ----
    #pragma unroll
    for (int rr = 0; rr < 4; rr++) {
        int n = min(ccnt[w][rr], CAP);
        if (n > KNN) {                    // wave-uniform branch
            bool act = lane < n;
            float ve = act ? cval[w][rr][lane] : -INFINITY;
            int   ie = act ? cidx[w][rr][lane] : 0x7FFFFFFF;
            int rk = 0;
            for (int f = 0; f < n; f++) {
                float vf = cval[w][rr][f];
                int   if_ = cidx[w][rr][f];
                rk += ((vf > ve) || (vf == ve && if_ < ie)) ? 1 : 0;
            }
            if (act && rk < KNN) sel[w][rr][rk] = ie;
        }
    }

    // ---- P3c: consume -- per-channel (lane) max over selected neighbors ----
    const float wa0 = sW0[lane * 6 + 0], wa1 = sW0[lane * 6 + 1], wa2 = sW0[lane * 6 + 2];
    const float wa0h = 0.5f * wa0, wa1h = 0.5f * wa1, wa2h = 0.5f * wa2;  // for p2 = 2p
    float mmax[4];
    #pragma unroll
    for (int rr = 0; rr < 4; rr++) mmax[rr] = -INFINITY;

    for (int tl = 0; tl < 2; tl++) {
        __syncthreads();
        STAGE_TILE(tl)
        __syncthreads();
        #pragma unroll
        for (int rr = 0; rr < 4; rr++) {
            int n = min(ccnt[w][rr], CAP);
            bool ranked = n > KNN;
            int cnt20 = ranked ? KNN : n;
            for (int e = 0; e < cnt20; e++) {
                int g = ranked ? sel[w][rr][e] : cidx[w][rr][e];   // uniform
                if ((g >> 11) == tl) {
                    float4 p = ptile[g & (TILE - 1)];
                    float dotp = fmaf(wa2h, p.z, fmaf(wa1h, p.y, wa0h * p.x));
                    mmax[rr] = fmaxf(mmax[rr], dotp);
                }
            }
        }
    }

    // conv = max_k(W0a.p_k) + (W0b-W0a).q ; (conv+b)*s+t ; lrelu.
    // s0>0 and lrelu monotone => max commutes past affine+activation.
    const float wd0 = sW0[lane * 6 + 3] - wa0;
    const float wd1 = sW0[lane * 6 + 4] - wa1;
    const float wd2 = sW0[lane * 6 + 5] - wa2;
    #pragma unroll
    for (int rr = 0; rr < 4; rr++) {
        float cterm = fmaf(wd2, qz[rr], fmaf(wd1, qy[rr], wd0 * qx[rr]));
        float z = (mmax[rr] + cterm + sB[lane]) * sS[lane] + sT[lane];
        H0[((size_t)(b * NPTS) + r0 + rr) * 64 + lane] = lrelu(z);
    }
#undef STAGE_TILE
}

// ---------------------------------------------------------------------------
// K2: pconv chain 64->64->128->128 + max over points.  1024 blocks x 256 thr.
//     Weights from global (L2-cached, lanes in an og-group share addresses);
//     only h tiles in LDS (~26 KB).
// ---------------------------------------------------------------------------
__global__ __launch_bounds__(256) void k2_mlp(
        const float* __restrict__ H0,
        const float* __restrict__ W1, const float* __restrict__ b1,
        const float* __restrict__ s1, const float* __restrict__ t1,
        const float* __restrict__ W2, const float* __restrict__ b2,
        const float* __restrict__ s2, const float* __restrict__ t2,
        const float* __restrict__ W3, const float* __restrict__ b3,
        const float* __restrict__ s3, const float* __restrict__ t3,
        uint32_t* __restrict__ gmax)
{
    __shared__ float A[32 * 132];     // h0 (64c) then aliased h2 (128c), stride 132
    __shared__ float h1[32 * 68];     // stride 68
    __shared__ uint32_t bmax[128];

    const int t = threadIdx.x;
    const int blk = blockIdx.x;
    const int b = blk >> 7;               // 128 blocks per batch
    const int pbase = (blk & 127) * 32;   // 32 points per block

    const int ps = t & 15;
    const int og = t >> 4;

    {
        const float4* src = (const float4*)&H0[((size_t)(b * NPTS) + pbase) * 64];
        #pragma unroll
        for (int k = 0; k < 2; k++) {
            int i4 = t * 2 + k;
            int p = i4 >> 4, c = (i4 & 15) * 4;
            *(float4*)&A[p * 132 + c] = src[i4];
        }
    }
    if (t < 128) bmax[t] = 0u;
    __syncthreads();

    // ---- L1: 64 -> 64 ----
    {
        float accA[4] = {0.f, 0.f, 0.f, 0.f};
        float accB[4] = {0.f, 0.f, 0.f, 0.f};
        for (int c = 0; c < 64; c += 4) {
            float4 hA = *(const float4*)&A[ps * 132 + c];
            float4 hB = *(const float4*)&A[(ps + 16) * 132 + c];
            #pragma unroll
            for (int r = 0; r < 4; r++) {
                float4 wv = *(const float4*)&W1[(og * 4 + r) * 64 + c];
                accA[r] += hA.x * wv.x + hA.y * wv.y + hA.z * wv.z + hA.w * wv.w;
                accB[r] += hB.x * wv.x + hB.y * wv.y + hB.z * wv.z + hB.w * wv.w;
            }
        }
        float4 oA, oB;
        float* pA = (float*)&oA; float* pB = (float*)&oB;
        #pragma unroll
        for (int r = 0; r < 4; r++) {
            int o = og * 4 + r;
            float bb = b1[o], ss = s1[o], tt = t1[o];
            pA[r] = lrelu((accA[r] + bb) * ss + tt);
            pB[r] = lrelu((accB[r] + bb) * ss + tt);
        }
        *(float4*)&h1[ps * 68 + og * 4] = oA;
        *(float4*)&h1[(ps + 16) * 68 + og * 4] = oB;
    }
    __syncthreads();

    // ---- L2: 64 -> 128 ----
    {
        float accA[8], accB[8];
        #pragma unroll
        for (int r = 0; r < 8; r++) { accA[r] = 0.f; accB[r] = 0.f; }
        for (int c = 0; c < 64; c += 4) {
            float4 hA = *(const float4*)&h1[ps * 68 + c];
            float4 hB = *(const float4*)&h1[(ps + 16) * 68 + c];
            #pragma unroll
            for (int r = 0; r < 8; r++) {
                float4 wv = *(const float4*)&W2[(og * 8 + r) * 64 + c];
                accA[r] += hA.x * wv.x + hA.y * wv.y + hA.z * wv.z + hA.w * wv.w;
                accB[r] += hB.x * wv.x + hB.y * wv.y + hB.z * wv.z + hB.w * wv.w;
            }
        }
        float4 oA[2], oB[2];
        float* pA = (float*)oA; float* pB = (float*)oB;
        #pragma unroll
        for (int r = 0; r < 8; r++) {
            int o = og * 8 + r;
            float bb = b2[o], ss = s2[o], tt = t2[o];
            pA[r] = lrelu((accA[r] + bb) * ss + tt);
            pB[r] = lrelu((accB[r] + bb) * ss + tt);
        }
        __syncthreads();
        *(float4*)&A[ps * 132 + og * 8]            = oA[0];
        *(float4*)&A[ps * 132 + og * 8 + 4]        = oA[1];
        *(float4*)&A[(ps + 16) * 132 + og * 8]     = oB[0];
        *(float4*)&A[(ps + 16) * 132 + og * 8 + 4] = oB[1];
    }
    __syncthreads();

    // ---- L3: 128 -> 128 + max over points ----
    {
        float accA[8], accB[8];
        #pragma unroll
        for (int r = 0; r < 8; r++) { accA[r] = 0.f; accB[r] = 0.f; }
        for (int c = 0; c < 128; c += 4) {
            float4 hA = *(const float4*)&A[ps * 132 + c];
            float4 hB = *(const float4*)&A[(ps + 16) * 132 + c];
            #pragma unroll
            for (int r = 0; r < 8; r++) {
                float4 wv = *(const float4*)&W3[(og * 8 + r) * 128 + c];
                accA[r] += hA.x * wv.x + hA.y * wv.y + hA.z * wv.z + hA.w * wv.w;
                accB[r] += hB.x * wv.x + hB.y * wv.y + hB.z * wv.z + hB.w * wv.w;
            }
        }
        float m[8];
        #pragma unroll
        for (int r = 0; r < 8; r++) m[r] = fmaxf(accA[r], accB[r]);
        #pragma unroll
        for (int off = 1; off < 16; off <<= 1) {
            #pragma unroll
            for (int r = 0; r < 8; r++)
                m[r] = fmaxf(m[r], __shfl_xor(m[r], off));
        }
        if (ps == 0) {
            #pragma unroll
            for (int r = 0; r < 8; r++) {
                int o = og * 8 + r;
                float z = lrelu((m[r] + b3[o]) * s3[o] + t3[o]);
                atomicMax(&bmax[o], enc_f32(z));
            }
        }
    }
    __syncthreads();
    if (t < 128) atomicMax(&gmax[b * 128 + t], bmax[t]);
}

// ---------------------------------------------------------------------------
// K3: head 128 -> 512 (affine+lrelu) -> 1024.  64 blocks (8 batch x 8 chunk).
// ---------------------------------------------------------------------------
__global__ __launch_bounds__(256) void k3_head(
        const uint32_t* __restrict__ gmax,
        const float* __restrict__ W4, const float* __restrict__ b4,
        const float* __restrict__ s4, const float* __restrict__ t4,
        const float* __restrict__ W5, const float* __restrict__ b5,
        float* __restrict__ out)
{
    __shared__ float sIn[128];
    __shared__ float sH4[512];
    const int t = threadIdx.x;
    const int b = blockIdx.x >> 3;
    const int chunk = blockIdx.x & 7;

    if (t < 128) sIn[t] = dec_f32(gmax[b * 128 + t]);
    __syncthreads();

    #pragma unroll
    for (int rep = 0; rep < 2; rep++) {
        int o = t + rep * 256;
        const float4* wr = (const float4*)&W4[(size_t)o * 128];
        float acc = 0.f;
        for (int c4 = 0; c4 < 32; c4++) {
            float4 wv = wr[c4];
            acc += sIn[c4 * 4] * wv.x + sIn[c4 * 4 + 1] * wv.y
                 + sIn[c4 * 4 + 2] * wv.z + sIn[c4 * 4 + 3] * wv.w;
        }
        float z = (acc + b4[o]) * s4[o] + t4[o];
        sH4[o] = lrelu(z);
    }
    __syncthreads();

    if (t < 128) {
        int o = chunk * 128 + t;
        const float4* wr = (const float4*)&W5[(size_t)o * 512];
        float acc = 0.f;
        for (int c4 = 0; c4 < 128; c4++) {
            float4 wv = wr[c4];
            acc += sH4[c4 * 4] * wv.x + sH4[c4 * 4 + 1] * wv.y
                 + sH4[c4 * 4 + 2] * wv.z + sH4[c4 * 4 + 3] * wv.w;
        }
        out[(size_t)b * 1024 + o] = acc + b5[o];
    }
}

// ---------------------------------------------------------------------------
extern "C" void kernel_launch(void* const* d_in, const int* in_sizes, int n_in,
                              void* d_out, int out_size, void* d_ws, size_t ws_size,
                              hipStream_t stream) {
    (void)in_sizes; (void)n_in; (void)out_size; (void)ws_size;
    const float* x  = (const float*)d_in[0];
    const float* W0 = (const float*)d_in[1];
    const float* b0 = (const float*)d_in[2];
    const float* s0 = (const float*)d_in[3];
    const float* t0 = (const float*)d_in[4];
    const float* W1 = (const float*)d_in[5];
    const float* b1 = (const float*)d_in[6];
    const float* s1 = (const float*)d_in[7];
    const float* t1 = (const float*)d_in[8];
    const float* W2 = (const float*)d_in[9];
    const float* b2 = (const float*)d_in[10];
    const float* s2 = (const float*)d_in[11];
    const float* t2 = (const float*)d_in[12];
    const float* W3 = (const float*)d_in[13];
    const float* b3 = (const float*)d_in[14];
    const float* s3 = (const float*)d_in[15];
    const float* t3 = (const float*)d_in[16];
    const float* W4 = (const float*)d_in[17];
    const float* b4 = (const float*)d_in[18];
    const float* s4 = (const float*)d_in[19];
    const float* t4 = (const float*)d_in[20];
    const float* W5 = (const float*)d_in[21];
    const float* b5 = (const float*)d_in[22];

    float* H0 = (float*)d_ws;                                  // [8][4096][64] f32 = 8 MB
    uint32_t* gmax = (uint32_t*)((char*)d_ws + (size_t)NB * NPTS * 64 * 4);  // [8][128] u32

    hipMemsetAsync(gmax, 0, NB * 128 * sizeof(uint32_t), stream);  // enc(-inf) floor

    k1_knn_edge<<<dim3(1024), dim3(512), 0, stream>>>(x, W0, b0, s0, t0, H0);
    k2_mlp<<<dim3(1024), dim3(256), 0, stream>>>(H0, W1, b1, s1, t1,
                                                 W2, b2, s2, t2,
                                                 W3, b3, s3, t3, gmax);
    k3_head<<<dim3(64), dim3(256), 0, stream>>>(gmax, W4, b4, s4, t4, W5, b5,
                                                (float*)d_out);
}

// Round 8
// 164.080 us; speedup vs baseline: 1.5794x; 1.1106x over previous
//
#include <hip/hip_runtime.h>
#include <hip/hip_bf16.h>
#include <cstdint>

#define NPTS 4096
#define NB 8
#define KNN 20
#define CAP 40          // collected-candidate capacity (n is ~20-24; 40 = huge slack)

__device__ __forceinline__ float lrelu(float x) { return x >= 0.0f ? x : 0.2f * x; }

// monotone float<->uint mapping (order-preserving for all finite floats)
__device__ __forceinline__ uint32_t enc_f32(float f) {
    uint32_t u = __float_as_uint(f);
    return (u & 0x80000000u) ? ~u : (u | 0x80000000u);
}
__device__ __forceinline__ float dec_f32(uint32_t u) {
    return (u & 0x80000000u) ? __uint_as_float(u ^ 0x80000000u) : __uint_as_float(~u);
}

// XOR bank swizzle: point i stored at phys(i).  Makes both the per-lane
// interleaved scan (fixed j, lane varies) and the cooperative lane-rescan
// (fixed L, lane varies) read a permutation of a contiguous 1KB block ->
// conflict-free ds_read_b128 in both phases.
__device__ __forceinline__ int physidx(int i) {
    return (i & ~63) | ((i ^ (i >> 6)) & 63);
}

// ---------------------------------------------------------------------------
// K1: fused kNN (top-20 smallest sq-dist, ties -> smaller index) + EdgeConv
//     (6->64) + max over k.  512-thr blocks, 4 rows/wave, full 4096-pt LDS
//     persist (one staging, one barrier).
//     P1: per-lane top-2 u-values  (u = 2 q.p - |p|^2, monotone in -dist)
//     P2: radix-ballot -> theta~ = 20th of the 128 lane-top-2s (<= true theta)
//     P3: collect u >= theta~ via cooperative lane-rescan of the ~18 lanes
//         with l0 >= theta~; exact rank when n > 20; consume from LDS.
// ---------------------------------------------------------------------------
__global__ __launch_bounds__(512, 4) void k1_knn_edge(
        const float* __restrict__ x,
        const float* __restrict__ W0, const float* __restrict__ b0,
        const float* __restrict__ s0, const float* __restrict__ t0,
        float* __restrict__ H0)
{
    __shared__ float4 pts[NPTS];          // 64 KB, swizzled, (2x,2y,2z,-|p|^2)
    __shared__ float  cval[8][4][CAP];    // 5 KB
    __shared__ int    cidx[8][4][CAP];    // 5 KB
    __shared__ int    sel[8][4][KNN];     // 2.5 KB
    __shared__ float  sW0[64 * 6];
    __shared__ float  sB[64], sS[64], sT[64];

    const int blk = blockIdx.x;
    const int b = blk >> 7;               // 128 blocks per batch
    const int rowbase = (blk & 127) << 5; // 32 rows per block
    const int t = threadIdx.x;
    const int lane = t & 63;
    const int w = t >> 6;                 // wave 0..7

    const float* xb = x + (size_t)b * (NPTS * 3);

    // ---- single staging of all 4096 points ----
    for (int i = t; i < NPTS; i += 512) {
        float x0 = xb[3 * i], x1 = xb[3 * i + 1], x2 = xb[3 * i + 2];
        float pp = __fadd_rn(__fadd_rn(__fmul_rn(x0, x0), __fmul_rn(x1, x1)),
                             __fmul_rn(x2, x2));
        pts[physidx(i)] = make_float4(x0 + x0, x1 + x1, x2 + x2, -pp);
    }
    if (t < 64) {
        #pragma unroll
        for (int c = 0; c < 6; c++) sW0[t * 6 + c] = W0[t * 6 + c];
        sB[t] = b0[t]; sS[t] = s0[t]; sT[t] = t0[t];
    }

    const int r0 = rowbase + w * 4;
    float qx[4], qy[4], qz[4];
    #pragma unroll
    for (int rr = 0; rr < 4; rr++) {
        qx[rr] = xb[3 * (r0 + rr) + 0];
        qy[rr] = xb[3 * (r0 + rr) + 1];
        qz[rr] = xb[3 * (r0 + rr) + 2];
    }
    __syncthreads();

    // ---- P1: per-lane top-2 values (lane's candidates: m = (j<<6)|lane) ----
    float l0[4], l1[4];
    #pragma unroll
    for (int rr = 0; rr < 4; rr++) { l0[rr] = -INFINITY; l1[rr] = -INFINITY; }

    #pragma unroll 4
    for (int j = 0; j < 64; j++) {
        const float4 p = pts[(j << 6) | ((lane ^ j) & 63)];
        #pragma unroll
        for (int rr = 0; rr < 4; rr++) {
            float u = fmaf(qx[rr], p.x, fmaf(qy[rr], p.y, fmaf(qz[rr], p.z, p.w)));
            float m1 = fminf(u, l0[rr]);
            l0[rr] = fmaxf(u, l0[rr]);
            l1[rr] = fmaxf(m1, l1[rr]);
        }
    }

    // ---- P2: radix-ballot theta~ (20th largest of the 128 lane-top-2s) ----
    uint32_t e0[4], e1[4], pr[4];
    #pragma unroll
    for (int rr = 0; rr < 4; rr++) {
        e0[rr] = enc_f32(l0[rr]);
        e1[rr] = enc_f32(l1[rr]);
        pr[rr] = 0u;
    }
    for (int bit = 31; bit >= 0; bit--) {
        #pragma unroll
        for (int rr = 0; rr < 4; rr++) {
            uint32_t T = pr[rr] | (1u << bit);
            int c = __popcll(__ballot(e0[rr] >= T)) + __popcll(__ballot(e1[rr] >= T));
            if (c >= KNN) pr[rr] = T;     // wave-uniform
        }
    }
    float th[4];
    #pragma unroll
    for (int rr = 0; rr < 4; rr++) th[rr] = dec_f32(pr[rr]);

    // ---- P3a: collect all u >= theta~ via cooperative lane-rescans ----
    // Any element >= theta~ is in a lane whose l0 >= theta~ (l0 >= u).
    // For each such lane L: lane j checks element (j<<6)|L  (1 elem/lane).
    int nsel[4];
    #pragma unroll
    for (int rr = 0; rr < 4; rr++) {
        int base = 0;
        unsigned long long lm = __ballot(l0[rr] >= th[rr]);
        while (lm) {
            int L = __ffsll(lm) - 1; lm &= lm - 1;          // uniform
            const float4 p = pts[(lane << 6) | ((L ^ lane) & 63)];
            float u = fmaf(qx[rr], p.x, fmaf(qy[rr], p.y, fmaf(qz[rr], p.z, p.w)));
            unsigned long long hit = __ballot(u >= th[rr]);
            if (u >= th[rr]) {
                int pos = base + __popcll(hit & ((1ull << lane) - 1ull));
                if (pos < CAP) {
                    cval[w][rr][pos] = u;
                    cidx[w][rr][pos] = (lane << 6) | L;
                }
            }
            base += __popcll(hit);
        }
        nsel[rr] = min(base, CAP);
    }

    // ---- P3b: exact top-20 by (value desc, idx asc) when n > 20 ----
    // (n == 20 unless float ties or a lane concentrated >2 of the top-20)
    #pragma unroll
    for (int rr = 0; rr < 4; rr++) {
        int n = nsel[rr];
        if (n > KNN) {                    // wave-uniform branch
            bool act = lane < n;
            float ve = act ? cval[w][rr][lane] : -INFINITY;
            int   ie = act ? cidx[w][rr][lane] : 0x7FFFFFFF;
            int rk = 0;
            for (int f = 0; f < n; f++) {
                float vf = cval[w][rr][f];
                int   if_ = cidx[w][rr][f];
                rk += ((vf > ve) || (vf == ve && if_ < ie)) ? 1 : 0;
            }
            if (act && rk < KNN) sel[w][rr][rk] = ie;
        }
    }

    // ---- P3c: consume -- per-channel (lane) max over selected neighbors ----
    const float wa0 = sW0[lane * 6 + 0], wa1 = sW0[lane * 6 + 1], wa2 = sW0[lane * 6 + 2];
    const float wa0h = 0.5f * wa0, wa1h = 0.5f * wa1, wa2h = 0.5f * wa2;  // pts hold 2p
    #pragma unroll
    for (int rr = 0; rr < 4; rr++) {
        int n = nsel[rr];
        bool ranked = n > KNN;
        int cnt20 = ranked ? KNN : n;
        float mm = -INFINITY;
        for (int e = 0; e < cnt20; e++) {
            int g = ranked ? sel[w][rr][e] : cidx[w][rr][e];   // uniform -> broadcast
            float4 p = pts[physidx(g)];
            float dotp = fmaf(wa2h, p.z, fmaf(wa1h, p.y, wa0h * p.x));
            mm = fmaxf(mm, dotp);
        }
        // conv = max_k(W0a.p_k) + (W0b-W0a).q ; (conv+b)*s+t ; lrelu.
        // s0>0 and lrelu monotone => max commutes past affine+activation.
        const float wd0 = sW0[lane * 6 + 3] - wa0;
        const float wd1 = sW0[lane * 6 + 4] - wa1;
        const float wd2 = sW0[lane * 6 + 5] - wa2;
        float cterm = fmaf(wd2, qz[rr], fmaf(wd1, qy[rr], wd0 * qx[rr]));
        float z = (mm + cterm + sB[lane]) * sS[lane] + sT[lane];
        H0[((size_t)(b * NPTS) + r0 + rr) * 64 + lane] = lrelu(z);
    }
}

// ---------------------------------------------------------------------------
// K2: pconv chain 64->64->128->128 + max over points.  1024 blocks x 256 thr.
//     Weights from global (L2-cached, lanes in an og-group share addresses);
//     only h tiles in LDS (~26 KB).
// ---------------------------------------------------------------------------
__global__ __launch_bounds__(256) void k2_mlp(
        const float* __restrict__ H0,
        const float* __restrict__ W1, const float* __restrict__ b1,
        const float* __restrict__ s1, const float* __restrict__ t1,
        const float* __restrict__ W2, const float* __restrict__ b2,
        const float* __restrict__ s2, const float* __restrict__ t2,
        const float* __restrict__ W3, const float* __restrict__ b3,
        const float* __restrict__ s3, const float* __restrict__ t3,
        uint32_t* __restrict__ gmax)
{
    __shared__ float A[32 * 132];     // h0 (64c) then aliased h2 (128c), stride 132
    __shared__ float h1[32 * 68];     // stride 68
    __shared__ uint32_t bmax[128];

    const int t = threadIdx.x;
    const int blk = blockIdx.x;
    const int b = blk >> 7;               // 128 blocks per batch
    const int pbase = (blk & 127) * 32;   // 32 points per block

    const int ps = t & 15;
    const int og = t >> 4;

    {
        const float4* src = (const float4*)&H0[((size_t)(b * NPTS) + pbase) * 64];
        #pragma unroll
        for (int k = 0; k < 2; k++) {
            int i4 = t * 2 + k;
            int p = i4 >> 4, c = (i4 & 15) * 4;
            *(float4*)&A[p * 132 + c] = src[i4];
        }
    }
    if (t < 128) bmax[t] = 0u;
    __syncthreads();

    // ---- L1: 64 -> 64 ----
    {
        float accA[4] = {0.f, 0.f, 0.f, 0.f};
        float accB[4] = {0.f, 0.f, 0.f, 0.f};
        for (int c = 0; c < 64; c += 4) {
            float4 hA = *(const float4*)&A[ps * 132 + c];
            float4 hB = *(const float4*)&A[(ps + 16) * 132 + c];
            #pragma unroll
            for (int r = 0; r < 4; r++) {
                float4 wv = *(const float4*)&W1[(og * 4 + r) * 64 + c];
                accA[r] += hA.x * wv.x + hA.y * wv.y + hA.z * wv.z + hA.w * wv.w;
                accB[r] += hB.x * wv.x + hB.y * wv.y + hB.z * wv.z + hB.w * wv.w;
            }
        }
        float4 oA, oB;
        float* pA = (float*)&oA; float* pB = (float*)&oB;
        #pragma unroll
        for (int r = 0; r < 4; r++) {
            int o = og * 4 + r;
            float bb = b1[o], ss = s1[o], tt = t1[o];
            pA[r] = lrelu((accA[r] + bb) * ss + tt);
            pB[r] = lrelu((accB[r] + bb) * ss + tt);
        }
        *(float4*)&h1[ps * 68 + og * 4] = oA;
        *(float4*)&h1[(ps + 16) * 68 + og * 4] = oB;
    }
    __syncthreads();

    // ---- L2: 64 -> 128 ----
    {
        float accA[8], accB[8];
        #pragma unroll
        for (int r = 0; r < 8; r++) { accA[r] = 0.f; accB[r] = 0.f; }
        for (int c = 0; c < 64; c += 4) {
            float4 hA = *(const float4*)&h1[ps * 68 + c];
            float4 hB = *(const float4*)&h1[(ps + 16) * 68 + c];
            #pragma unroll
            for (int r = 0; r < 8; r++) {
                float4 wv = *(const float4*)&W2[(og * 8 + r) * 64 + c];
                accA[r] += hA.x * wv.x + hA.y * wv.y + hA.z * wv.z + hA.w * wv.w;
                accB[r] += hB.x * wv.x + hB.y * wv.y + hB.z * wv.z + hB.w * wv.w;
            }
        }
        float4 oA[2], oB[2];
        float* pA = (float*)oA; float* pB = (float*)oB;
        #pragma unroll
        for (int r = 0; r < 8; r++) {
            int o = og * 8 + r;
            float bb = b2[o], ss = s2[o], tt = t2[o];
            pA[r] = lrelu((accA[r] + bb) * ss + tt);
            pB[r] = lrelu((accB[r] + bb) * ss + tt);
        }
        __syncthreads();
        *(float4*)&A[ps * 132 + og * 8]            = oA[0];
        *(float4*)&A[ps * 132 + og * 8 + 4]        = oA[1];
        *(float4*)&A[(ps + 16) * 132 + og * 8]     = oB[0];
        *(float4*)&A[(ps + 16) * 132 + og * 8 + 4] = oB[1];
    }
    __syncthreads();

    // ---- L3: 128 -> 128 + max over points ----
    {
        float accA[8], accB[8];
        #pragma unroll
        for (int r = 0; r < 8; r++) { accA[r] = 0.f; accB[r] = 0.f; }
        for (int c = 0; c < 128; c += 4) {
            float4 hA = *(const float4*)&A[ps * 132 + c];
            float4 hB = *(const float4*)&A[(ps + 16) * 132 + c];
            #pragma unroll
            for (int r = 0; r < 8; r++) {
                float4 wv = *(const float4*)&W3[(og * 8 + r) * 128 + c];
                accA[r] += hA.x * wv.x + hA.y * wv.y + hA.z * wv.z + hA.w * wv.w;
                accB[r] += hB.x * wv.x + hB.y * wv.y + hB.z * wv.z + hB.w * wv.w;
            }
        }
        float m[8];
        #pragma unroll
        for (int r = 0; r < 8; r++) m[r] = fmaxf(accA[r], accB[r]);
        #pragma unroll
        for (int off = 1; off < 16; off <<= 1) {
            #pragma unroll
            for (int r = 0; r < 8; r++)
                m[r] = fmaxf(m[r], __shfl_xor(m[r], off));
        }
        if (ps == 0) {
            #pragma unroll
            for (int r = 0; r < 8; r++) {
                int o = og * 8 + r;
                float z = lrelu((m[r] + b3[o]) * s3[o] + t3[o]);
                atomicMax(&bmax[o], enc_f32(z));
            }
        }
    }
    __syncthreads();
    if (t < 128) atomicMax(&gmax[b * 128 + t], bmax[t]);
}

// ---------------------------------------------------------------------------
// K3: head 128 -> 512 (affine+lrelu) -> 1024.  64 blocks (8 batch x 8 chunk).
// ---------------------------------------------------------------------------
__global__ __launch_bounds__(256) void k3_head(
        const uint32_t* __restrict__ gmax,
        const float* __restrict__ W4, const float* __restrict__ b4,
        const float* __restrict__ s4, const float* __restrict__ t4,
        const float* __restrict__ W5, const float* __restrict__ b5,
        float* __restrict__ out)
{
    __shared__ float sIn[128];
    __shared__ float sH4[512];
    const int t = threadIdx.x;
    const int b = blockIdx.x >> 3;
    const int chunk = blockIdx.x & 7;

    if (t < 128) sIn[t] = dec_f32(gmax[b * 128 + t]);
    __syncthreads();

    #pragma unroll
    for (int rep = 0; rep < 2; rep++) {
        int o = t + rep * 256;
        const float4* wr = (const float4*)&W4[(size_t)o * 128];
        float acc = 0.f;
        for (int c4 = 0; c4 < 32; c4++) {
            float4 wv = wr[c4];
            acc += sIn[c4 * 4] * wv.x + sIn[c4 * 4 + 1] * wv.y
                 + sIn[c4 * 4 + 2] * wv.z + sIn[c4 * 4 + 3] * wv.w;
        }
        float z = (acc + b4[o]) * s4[o] + t4[o];
        sH4[o] = lrelu(z);
    }
    __syncthreads();

    if (t < 128) {
        int o = chunk * 128 + t;
        const float4* wr = (const float4*)&W5[(size_t)o * 512];
        float acc = 0.f;
        for (int c4 = 0; c4 < 128; c4++) {
            float4 wv = wr[c4];
            acc += sH4[c4 * 4] * wv.x + sH4[c4 * 4 + 1] * wv.y
                 + sH4[c4 * 4 + 2] * wv.z + sH4[c4 * 4 + 3] * wv.w;
        }
        out[(size_t)b * 1024 + o] = acc + b5[o];
    }
}

// ---------------------------------------------------------------------------
extern "C" void kernel_launch(void* const* d_in, const int* in_sizes, int n_in,
                              void* d_out, int out_size, void* d_ws, size_t ws_size,
                              hipStream_t stream) {
    (void)in_sizes; (void)n_in; (void)out_size; (void)ws_size;
    const float* x  = (const float*)d_in[0];
    const float* W0 = (const float*)d_in[1];
    const float* b0 = (const float*)d_in[2];
    const float* s0 = (const float*)d_in[3];
    const float* t0 = (const float*)d_in[4];
    const float* W1 = (const float*)d_in[5];
    const float* b1 = (const float*)d_in[6];
    const float* s1 = (const float*)d_in[7];
    const float* t1 = (const float*)d_in[8];
    const float* W2 = (const float*)d_in[9];
    const float* b2 = (const float*)d_in[10];
    const float* s2 = (const float*)d_in[11];
    const float* t2 = (const float*)d_in[12];
    const float* W3 = (const float*)d_in[13];
    const float* b3 = (const float*)d_in[14];
    const float* s3 = (const float*)d_in[15];
    const float* t3 = (const float*)d_in[16];
    const float* W4 = (const float*)d_in[17];
    const float* b4 = (const float*)d_in[18];
    const float* s4 = (const float*)d_in[19];
    const float* t4 = (const float*)d_in[20];
    const float* W5 = (const float*)d_in[21];
    const float* b5 = (const float*)d_in[22];

    float* H0 = (float*)d_ws;                                  // [8][4096][64] f32 = 8 MB
    uint32_t* gmax = (uint32_t*)((char*)d_ws + (size_t)NB * NPTS * 64 * 4);  // [8][128] u32

    hipMemsetAsync(gmax, 0, NB * 128 * sizeof(uint32_t), stream);  // enc(-inf) floor

    k1_knn_edge<<<dim3(1024), dim3(512), 0, stream>>>(x, W0, b0, s0, t0, H0);
    k2_mlp<<<dim3(1024), dim3(256), 0, stream>>>(H0, W1, b1, s1, t1,
                                                 W2, b2, s2, t2,
                                                 W3, b3, s3, t3, gmax);
    k3_head<<<dim3(64), dim3(256), 0, stream>>>(gmax, W4, b4, s4, t4, W5, b5,
                                                (float*)d_out);
}

// Round 9
// 148.489 us; speedup vs baseline: 1.7453x; 1.1050x over previous
//
#include <hip/hip_runtime.h>
#include <hip/hip_bf16.h>
#include <cstdint>

#define NPTS 4096
#define NB 8
#define KNN 20
#define CAP 40          // collected-candidate capacity (n ~20-24; 40 = big slack)

__device__ __forceinline__ float lrelu(float x) { return x >= 0.0f ? x : 0.2f * x; }

// monotone float<->uint mapping (order-preserving for all finite floats)
__device__ __forceinline__ uint32_t enc_f32(float f) {
    uint32_t u = __float_as_uint(f);
    return (u & 0x80000000u) ? ~u : (u | 0x80000000u);
}
__device__ __forceinline__ float dec_f32(uint32_t u) {
    return (u & 0x80000000u) ? __uint_as_float(u ^ 0x80000000u) : __uint_as_float(~u);
}

// XOR bank swizzle: point i stored at phys(i).  Both the per-lane interleaved
// scan and the cooperative lane-rescan then read permutations of contiguous
// 1KB blocks -> conflict-free ds_read_b128 (verified R8: conflicts 110K -> 0).
__device__ __forceinline__ int physidx(int i) {
    return (i & ~63) | ((i ^ (i >> 6)) & 63);
}

// ---------------------------------------------------------------------------
// K1: fused kNN (top-20 smallest sq-dist, ties -> smaller index) + EdgeConv
//     (6->64) + max over k.  512-thr blocks, 8 rows/wave (64 rows/block,
//     grid 512 -> fully co-resident), full 4096-pt LDS persist.
//     P1: per-lane top-2 u-values over 8 rows  (u = 2 q.p - |p|^2)
//     P2: 16-bit radix-ballot -> theta~ <= true 20th value  (2 halves x 4 rows)
//     P3: cooperative collect u >= theta~ ; exact rank if n > 20; consume.
// ---------------------------------------------------------------------------
__global__ __launch_bounds__(512, 4) void k1_knn_edge(
        const float* __restrict__ x,
        const float* __restrict__ W0, const float* __restrict__ b0,
        const float* __restrict__ s0, const float* __restrict__ t0,
        float* __restrict__ H0)
{
    __shared__ float4 pts[NPTS];          // 64 KB, swizzled, (2x,2y,2z,-|p|^2)
    __shared__ float  cval[8][4][CAP];    // 5 KB
    __shared__ int    cidx[8][4][CAP];    // 5 KB
    __shared__ int    sel[8][4][KNN];     // 2.5 KB
    __shared__ float  sW0[64 * 6];
    __shared__ float  sB[64], sS[64], sT[64];

    const int blk = blockIdx.x;
    const int b = blk >> 6;               // 64 blocks per batch
    const int rowbase = (blk & 63) << 6;  // 64 rows per block
    const int t = threadIdx.x;
    const int lane = t & 63;
    const int w = t >> 6;                 // wave 0..7

    const float* xb = x + (size_t)b * (NPTS * 3);

    // ---- single staging of all 4096 points ----
    for (int i = t; i < NPTS; i += 512) {
        float x0 = xb[3 * i], x1 = xb[3 * i + 1], x2 = xb[3 * i + 2];
        float pp = __fadd_rn(__fadd_rn(__fmul_rn(x0, x0), __fmul_rn(x1, x1)),
                             __fmul_rn(x2, x2));
        pts[physidx(i)] = make_float4(x0 + x0, x1 + x1, x2 + x2, -pp);
    }
    if (t < 64) {
        #pragma unroll
        for (int c = 0; c < 6; c++) sW0[t * 6 + c] = W0[t * 6 + c];
        sB[t] = b0[t]; sS[t] = s0[t]; sT[t] = t0[t];
    }

    const int r0 = rowbase + w * 8;
    float qx[8], qy[8], qz[8];
    #pragma unroll
    for (int rr = 0; rr < 8; rr++) {
        qx[rr] = xb[3 * (r0 + rr) + 0];
        qy[rr] = xb[3 * (r0 + rr) + 1];
        qz[rr] = xb[3 * (r0 + rr) + 2];
    }
    __syncthreads();

    // ---- P1: per-lane top-2 values for 8 rows ----
    float l0[8], l1[8];
    #pragma unroll
    for (int rr = 0; rr < 8; rr++) { l0[rr] = -INFINITY; l1[rr] = -INFINITY; }

    #pragma unroll 4
    for (int j = 0; j < 64; j++) {
        const float4 p = pts[(j << 6) | ((lane ^ j) & 63)];
        #pragma unroll
        for (int rr = 0; rr < 8; rr++) {
            float u = fmaf(qx[rr], p.x, fmaf(qy[rr], p.y, fmaf(qz[rr], p.z, p.w)));
            float m1 = fminf(u, l0[rr]);
            l0[rr] = fmaxf(u, l0[rr]);
            l1[rr] = fmaxf(m1, l1[rr]);
        }
    }

    const float wa0 = sW0[lane * 6 + 0], wa1 = sW0[lane * 6 + 1], wa2 = sW0[lane * 6 + 2];
    const float wa0h = 0.5f * wa0, wa1h = 0.5f * wa1, wa2h = 0.5f * wa2;  // pts hold 2p
    const float wd0 = sW0[lane * 6 + 3] - wa0;
    const float wd1 = sW0[lane * 6 + 4] - wa1;
    const float wd2 = sW0[lane * 6 + 5] - wa2;

    // ---- process rows in two halves of 4 (keeps collect-LDS small) ----
    for (int half = 0; half < 2; half++) {
        const int R = half * 4;

        // P2: 16-bit radix-ballot theta~ (bits 31..16 of enc).
        // Sound: count(lane-top-2 >= pr) >= 20 => true 20th >= pr.
        uint32_t e0[4], e1[4], pr[4];
        #pragma unroll
        for (int rr = 0; rr < 4; rr++) {
            e0[rr] = enc_f32(l0[R + rr]);
            e1[rr] = enc_f32(l1[R + rr]);
            pr[rr] = 0u;
        }
        for (int bit = 31; bit >= 16; bit--) {
            #pragma unroll
            for (int rr = 0; rr < 4; rr++) {
                uint32_t T = pr[rr] | (1u << bit);
                int c = __popcll(__ballot(e0[rr] >= T)) + __popcll(__ballot(e1[rr] >= T));
                if (c >= KNN) pr[rr] = T;     // wave-uniform
            }
        }
        float th[4];
        #pragma unroll
        for (int rr = 0; rr < 4; rr++) th[rr] = dec_f32(pr[rr]);

        // P3a: collect all u >= theta~ via cooperative lane-rescans.
        // Any element >= theta~ lives in a lane whose l0 >= theta~.
        int nsel[4];
        #pragma unroll
        for (int rr = 0; rr < 4; rr++) {
            int base = 0;
            unsigned long long lm = __ballot(l0[R + rr] >= th[rr]);
            while (lm) {
                int L = __ffsll(lm) - 1; lm &= lm - 1;          // uniform
                const float4 p = pts[(lane << 6) | ((L ^ lane) & 63)];
                float u = fmaf(qx[R + rr], p.x,
                          fmaf(qy[R + rr], p.y, fmaf(qz[R + rr], p.z, p.w)));
                unsigned long long hit = __ballot(u >= th[rr]);
                if (u >= th[rr]) {
                    int pos = base + __popcll(hit & ((1ull << lane) - 1ull));
                    if (pos < CAP) {
                        cval[w][rr][pos] = u;
                        cidx[w][rr][pos] = (lane << 6) | L;
                    }
                }
                base += __popcll(hit);
            }
            nsel[rr] = min(base, CAP);
        }

        // P3b: exact top-20 by (value desc, idx asc) when n > 20
        #pragma unroll
        for (int rr = 0; rr < 4; rr++) {
            int n = nsel[rr];
            if (n > KNN) {                    // wave-uniform branch
                bool act = lane < n;
                float ve = act ? cval[w][rr][lane] : -INFINITY;
                int   ie = act ? cidx[w][rr][lane] : 0x7FFFFFFF;
                int rk = 0;
                for (int f = 0; f < n; f++) {
                    float vf = cval[w][rr][f];
                    int   if_ = cidx[w][rr][f];
                    rk += ((vf > ve) || (vf == ve && if_ < ie)) ? 1 : 0;
                }
                if (act && rk < KNN) sel[w][rr][rk] = ie;
            }
        }

        // P3c: consume -- per-channel (lane) max over selected neighbors
        #pragma unroll
        for (int rr = 0; rr < 4; rr++) {
            int n = nsel[rr];
            bool ranked = n > KNN;
            int cnt20 = ranked ? KNN : n;
            float mm = -INFINITY;
            for (int e = 0; e < cnt20; e++) {
                int g = ranked ? sel[w][rr][e] : cidx[w][rr][e];   // uniform
                float4 p = pts[physidx(g)];
                float dotp = fmaf(wa2h, p.z, fmaf(wa1h, p.y, wa0h * p.x));
                mm = fmaxf(mm, dotp);
            }
            // conv = max_k(W0a.p_k) + (W0b-W0a).q ; (conv+b)*s+t ; lrelu.
            // s0>0 and lrelu monotone => max commutes past affine+activation.
            float cterm = fmaf(wd2, qz[R + rr], fmaf(wd1, qy[R + rr], wd0 * qx[R + rr]));
            float z = (mm + cterm + sB[lane]) * sS[lane] + sT[lane];
            H0[((size_t)(b * NPTS) + r0 + R + rr) * 64 + lane] = lrelu(z);
        }
    }
}

// ---------------------------------------------------------------------------
// K2: pconv chain 64->64->128->128 + max over points.  1024 blocks x 128 thr,
//     4 points per thread (weight loads amortized 2x vs R8).  Weights from
//     global (L2-cached, og-group lanes share addresses); h tiles in LDS.
//     Thread = (ps 0..7, og 0..15); points {ps, ps+8, ps+16, ps+24}.
// ---------------------------------------------------------------------------
__global__ __launch_bounds__(128, 2) void k2_mlp(
        const float* __restrict__ H0,
        const float* __restrict__ W1, const float* __restrict__ b1,
        const float* __restrict__ s1, const float* __restrict__ t1,
        const float* __restrict__ W2, const float* __restrict__ b2,
        const float* __restrict__ s2, const float* __restrict__ t2,
        const float* __restrict__ W3, const float* __restrict__ b3,
        const float* __restrict__ s3, const float* __restrict__ t3,
        uint32_t* __restrict__ gmax)
{
    __shared__ float A[32 * 132];     // h0 (64c) then aliased h2 (128c), stride 132
    __shared__ float h1[32 * 68];     // stride 68
    __shared__ uint32_t bmax[128];

    const int t = threadIdx.x;            // 128 threads
    const int blk = blockIdx.x;
    const int b = blk >> 7;               // 128 blocks per batch
    const int pbase = (blk & 127) * 32;   // 32 points per block

    const int ps = t & 7;                 // 0..7
    const int og = t >> 3;                // 0..15

    // stage h0 tile [32 pts][64 ch] -> A (stride 132): 512 float4, 4/thread
    {
        const float4* src = (const float4*)&H0[((size_t)(b * NPTS) + pbase) * 64];
        #pragma unroll
        for (int k = 0; k < 4; k++) {
            int i4 = t * 4 + k;
            int p = i4 >> 4, c = (i4 & 15) * 4;
            *(float4*)&A[p * 132 + c] = src[i4];
        }
    }
    bmax[t] = 0u;
    __syncthreads();

    // ---- L1: 64 -> 64 ; outs o = og*4+[0,4), pts {ps+8*pp} ----
    {
        float acc[4][4] = {};
        for (int c = 0; c < 64; c += 4) {
            float4 h[4];
            #pragma unroll
            for (int pp = 0; pp < 4; pp++)
                h[pp] = *(const float4*)&A[(ps + 8 * pp) * 132 + c];
            #pragma unroll
            for (int r = 0; r < 4; r++) {
                float4 wv = *(const float4*)&W1[(og * 4 + r) * 64 + c];
                #pragma unroll
                for (int pp = 0; pp < 4; pp++)
                    acc[pp][r] += h[pp].x * wv.x + h[pp].y * wv.y
                                + h[pp].z * wv.z + h[pp].w * wv.w;
            }
        }
        #pragma unroll
        for (int pp = 0; pp < 4; pp++) {
            float4 o4; float* po = (float*)&o4;
            #pragma unroll
            for (int r = 0; r < 4; r++) {
                int o = og * 4 + r;
                po[r] = lrelu((acc[pp][r] + b1[o]) * s1[o] + t1[o]);
            }
            *(float4*)&h1[(ps + 8 * pp) * 68 + og * 4] = o4;
        }
    }
    __syncthreads();

    // ---- L2: 64 -> 128 ; outs o = og*8+[0,8) ; h2 overwrites A ----
    {
        float acc[4][8] = {};
        for (int c = 0; c < 64; c += 4) {
            float4 h[4];
            #pragma unroll
            for (int pp = 0; pp < 4; pp++)
                h[pp] = *(const float4*)&h1[(ps + 8 * pp) * 68 + c];
            #pragma unroll
            for (int r = 0; r < 8; r++) {
                float4 wv = *(const float4*)&W2[(og * 8 + r) * 64 + c];
                #pragma unroll
                for (int pp = 0; pp < 4; pp++)
                    acc[pp][r] += h[pp].x * wv.x + h[pp].y * wv.y
                                + h[pp].z * wv.z + h[pp].w * wv.w;
            }
        }
        __syncthreads();   // everyone done reading A (h0) before overwriting
        #pragma unroll
        for (int pp = 0; pp < 4; pp++) {
            float4 o4a, o4b; float* pa = (float*)&o4a; float* pb = (float*)&o4b;
            #pragma unroll
            for (int r = 0; r < 4; r++) {
                int o = og * 8 + r;
                pa[r] = lrelu((acc[pp][r] + b2[o]) * s2[o] + t2[o]);
            }
            #pragma unroll
            for (int r = 4; r < 8; r++) {
                int o = og * 8 + r;
                pb[r - 4] = lrelu((acc[pp][r] + b2[o]) * s2[o] + t2[o]);
            }
            *(float4*)&A[(ps + 8 * pp) * 132 + og * 8]     = o4a;
            *(float4*)&A[(ps + 8 * pp) * 132 + og * 8 + 4] = o4b;
        }
    }
    __syncthreads();

    // ---- L3: 128 -> 128 + max over points ----
    {
        float acc[4][8] = {};
        for (int c = 0; c < 128; c += 4) {
            float4 h[4];
            #pragma unroll
            for (int pp = 0; pp < 4; pp++)
                h[pp] = *(const float4*)&A[(ps + 8 * pp) * 132 + c];
            #pragma unroll
            for (int r = 0; r < 8; r++) {
                float4 wv = *(const float4*)&W3[(og * 8 + r) * 128 + c];
                #pragma unroll
                for (int pp = 0; pp < 4; pp++)
                    acc[pp][r] += h[pp].x * wv.x + h[pp].y * wv.y
                                + h[pp].z * wv.z + h[pp].w * wv.w;
            }
        }
        // max over own 4 points (pre-affine: s3>0, monotone), then across ps
        float m[8];
        #pragma unroll
        for (int r = 0; r < 8; r++)
            m[r] = fmaxf(fmaxf(acc[0][r], acc[1][r]), fmaxf(acc[2][r], acc[3][r]));
        #pragma unroll
        for (int off = 1; off < 8; off <<= 1) {
            #pragma unroll
            for (int r = 0; r < 8; r++)
                m[r] = fmaxf(m[r], __shfl_xor(m[r], off));
        }
        if (ps == 0) {
            #pragma unroll
            for (int r = 0; r < 8; r++) {
                int o = og * 8 + r;
                float z = lrelu((m[r] + b3[o]) * s3[o] + t3[o]);
                atomicMax(&bmax[o], enc_f32(z));
            }
        }
    }
    __syncthreads();
    atomicMax(&gmax[b * 128 + t], bmax[t]);
}

// ---------------------------------------------------------------------------
// K3: head 128 -> 512 (affine+lrelu) -> 1024.  64 blocks (8 batch x 8 chunk).
// ---------------------------------------------------------------------------
__global__ __launch_bounds__(256) void k3_head(
        const uint32_t* __restrict__ gmax,
        const float* __restrict__ W4, const float* __restrict__ b4,
        const float* __restrict__ s4, const float* __restrict__ t4,
        const float* __restrict__ W5, const float* __restrict__ b5,
        float* __restrict__ out)
{
    __shared__ float sIn[128];
    __shared__ float sH4[512];
    const int t = threadIdx.x;
    const int b = blockIdx.x >> 3;
    const int chunk = blockIdx.x & 7;

    if (t < 128) sIn[t] = dec_f32(gmax[b * 128 + t]);
    __syncthreads();

    #pragma unroll
    for (int rep = 0; rep < 2; rep++) {
        int o = t + rep * 256;
        const float4* wr = (const float4*)&W4[(size_t)o * 128];
        float acc = 0.f;
        for (int c4 = 0; c4 < 32; c4++) {
            float4 wv = wr[c4];
            acc += sIn[c4 * 4] * wv.x + sIn[c4 * 4 + 1] * wv.y
                 + sIn[c4 * 4 + 2] * wv.z + sIn[c4 * 4 + 3] * wv.w;
        }
        float z = (acc + b4[o]) * s4[o] + t4[o];
        sH4[o] = lrelu(z);
    }
    __syncthreads();

    if (t < 128) {
        int o = chunk * 128 + t;
        const float4* wr = (const float4*)&W5[(size_t)o * 512];
        float acc = 0.f;
        for (int c4 = 0; c4 < 128; c4++) {
            float4 wv = wr[c4];
            acc += sH4[c4 * 4] * wv.x + sH4[c4 * 4 + 1] * wv.y
                 + sH4[c4 * 4 + 2] * wv.z + sH4[c4 * 4 + 3] * wv.w;
        }
        out[(size_t)b * 1024 + o] = acc + b5[o];
    }
}

// ---------------------------------------------------------------------------
extern "C" void kernel_launch(void* const* d_in, const int* in_sizes, int n_in,
                              void* d_out, int out_size, void* d_ws, size_t ws_size,
                              hipStream_t stream) {
    (void)in_sizes; (void)n_in; (void)out_size; (void)ws_size;
    const float* x  = (const float*)d_in[0];
    const float* W0 = (const float*)d_in[1];
    const float* b0 = (const float*)d_in[2];
    const float* s0 = (const float*)d_in[3];
    const float* t0 = (const float*)d_in[4];
    const float* W1 = (const float*)d_in[5];
    const float* b1 = (const float*)d_in[6];
    const float* s1 = (const float*)d_in[7];
    const float* t1 = (const float*)d_in[8];
    const float* W2 = (const float*)d_in[9];
    const float* b2 = (const float*)d_in[10];
    const float* s2 = (const float*)d_in[11];
    const float* t2 = (const float*)d_in[12];
    const float* W3 = (const float*)d_in[13];
    const float* b3 = (const float*)d_in[14];
    const float* s3 = (const float*)d_in[15];
    const float* t3 = (const float*)d_in[16];
    const float* W4 = (const float*)d_in[17];
    const float* b4 = (const float*)d_in[18];
    const float* s4 = (const float*)d_in[19];
    const float* t4 = (const float*)d_in[20];
    const float* W5 = (const float*)d_in[21];
    const float* b5 = (const float*)d_in[22];

    float* H0 = (float*)d_ws;                                  // [8][4096][64] f32 = 8 MB
    uint32_t* gmax = (uint32_t*)((char*)d_ws + (size_t)NB * NPTS * 64 * 4);  // [8][128] u32

    hipMemsetAsync(gmax, 0, NB * 128 * sizeof(uint32_t), stream);  // enc(-inf) floor

    k1_knn_edge<<<dim3(512), dim3(512), 0, stream>>>(x, W0, b0, s0, t0, H0);
    k2_mlp<<<dim3(1024), dim3(128), 0, stream>>>(H0, W1, b1, s1, t1,
                                                 W2, b2, s2, t2,
                                                 W3, b3, s3, t3, gmax);
    k3_head<<<dim3(64), dim3(256), 0, stream>>>(gmax, W4, b4, s4, t4, W5, b5,
                                                (float*)d_out);
}